// Round 11
// baseline (361.457 us; speedup 1.0000x reference)
//
#include <hip/hip_runtime.h>
#include <hip/hip_bf16.h>

#define S_SP 16384
#define NKV 512

typedef short short8 __attribute__((ext_vector_type(8)));
typedef float v4f   __attribute__((ext_vector_type(4)));
typedef float v2f   __attribute__((ext_vector_type(2)));

__device__ __forceinline__ unsigned short f2bf(float x){
  union { float f; unsigned u; } v; v.f = x;
  unsigned r = v.u + 0x7FFFu + ((v.u >> 16) & 1u);
  return (unsigned short)(r >> 16);
}
__device__ __forceinline__ float bf2f(unsigned short h){
  union { unsigned u; float f; } v; v.u = ((unsigned)h) << 16; return v.f;
}

#if defined(__has_builtin)
#if __has_builtin(__builtin_amdgcn_cvt_pk_bf16_f32)
#define HAVE_PKBF 1
#endif
#endif

__device__ __forceinline__ unsigned pk2(float a, float b){
#ifdef HAVE_PKBF
  typedef __bf16 bf16x2 __attribute__((ext_vector_type(2)));
  union { bf16x2 v; unsigned u; } r;
  r.v = __builtin_amdgcn_cvt_pk_bf16_f32(a, b);
  return r.u;
#else
  return (unsigned)f2bf(a) | ((unsigned)f2bf(b) << 16);
#endif
}

__device__ __forceinline__ short8 u2s8(uint4 u){
  union { uint4 u; short8 s; } x; x.u = u; return x.s;
}

// async global->LDS, 16B/lane; LDS dest = wave-uniform base + lane*16
__device__ __forceinline__ void gll16(const unsigned short* g, unsigned short* l){
  __builtin_amdgcn_global_load_lds(
    (const __attribute__((address_space(1))) unsigned int*)g,
    (__attribute__((address_space(3))) unsigned int*)l, 16, 0, 0);
}

// ---------------- K1: channel-LN stats + pre-LN'd transposed bf16 hi/lo copy
// Blocks [0,1024): stats + XT emit (float2 input loads: 16 x 8B per thread).
// Blocks [1024,1088): W hi/lo split.
__global__ __launch_bounds__(256) void k_stats(const float* __restrict__ ctx,
                                               const float* __restrict__ qs,
                                               const float* __restrict__ ctx_g,
                                               const float* __restrict__ ctx_b,
                                               const float* __restrict__ qs_g,
                                               const float* __restrict__ qs_b,
                                               const float* __restrict__ wq,
                                               const float* __restrict__ wkv,
                                               float* __restrict__ MEAN,
                                               float* __restrict__ INV,
                                               unsigned short* __restrict__ XTC_hi,
                                               unsigned short* __restrict__ XTC_lo,
                                               unsigned short* __restrict__ XTQ_hi,
                                               unsigned short* __restrict__ XTQ_lo,
                                               unsigned short* __restrict__ WQh,
                                               unsigned short* __restrict__ WQl,
                                               unsigned short* __restrict__ WKh,
                                               unsigned short* __restrict__ WKl){
  __shared__ float r1[8][64];
  __shared__ float r2[8][64];
  __shared__ float mb[64], ib[64];
  __shared__ __align__(16) unsigned short TH[64*136];
  __shared__ __align__(16) unsigned short TL[64*136];
  int bx = blockIdx.x;
  int t = threadIdx.x;
  if (bx >= 1024){ // W hi/lo split: wq (512x128) then wkv K-half (512x128)
    int wb = bx - 1024;
    int isK = wb >> 5;
    size_t i8 = ((size_t)(wb & 31)*256 + t)*8;
    const float* srcw = isK ? wkv : wq;
    unsigned short* dh = isK ? WKh : WQh;
    unsigned short* dl = isK ? WKl : WQl;
    v4f a  = *(const v4f*)(srcw + i8);
    v4f b2 = *(const v4f*)(srcw + i8 + 4);
    unsigned short h[8], l[8];
    #pragma unroll
    for (int i=0;i<4;i++){
      h[i]   = f2bf(a[i]);  l[i]   = f2bf(a[i]  - bf2f(h[i]));
      h[i+4] = f2bf(b2[i]); l[i+4] = f2bf(b2[i] - bf2f(h[i+4]));
    }
    uint4 uh, ul;
    uh.x = (unsigned)h[0] | ((unsigned)h[1]<<16);
    uh.y = (unsigned)h[2] | ((unsigned)h[3]<<16);
    uh.z = (unsigned)h[4] | ((unsigned)h[5]<<16);
    uh.w = (unsigned)h[6] | ((unsigned)h[7]<<16);
    ul.x = (unsigned)l[0] | ((unsigned)l[1]<<16);
    ul.y = (unsigned)l[2] | ((unsigned)l[3]<<16);
    ul.z = (unsigned)l[4] | ((unsigned)l[5]<<16);
    ul.w = (unsigned)l[6] | ((unsigned)l[7]<<16);
    *(uint4*)(dh + i8) = uh;
    *(uint4*)(dl + i8) = ul;
    return;
  }
  int tt = bx >> 9; int b = (bx >> 8) & 1; int sc = bx & 255;
  int cg = t >> 5, sv2 = t & 31;      // 8 c-groups x 16c, 32 s-pairs
  int s0 = sc*64;
  const float* src = (tt ? qs : ctx) + ((size_t)(b*128 + cg*16))*S_SP + s0 + sv2*2;
  const float* G  = tt ? qs_g : ctx_g;
  const float* Bv = tt ? qs_b : ctx_b;
  float xa[16], xb[16];
  float sa = 0.f, sb = 0.f, qa = 0.f, qb2 = 0.f;
  #pragma unroll
  for (int i = 0; i < 16; i++){
    v2f v = *(const v2f*)(src + (size_t)i*S_SP);
    xa[i] = v[0]; xb[i] = v[1];
    sa += v[0]; qa += v[0]*v[0];
    sb += v[1]; qb2 += v[1]*v[1];
  }
  r1[cg][sv2*2]   = sa; r1[cg][sv2*2+1] = sb;
  r2[cg][sv2*2]   = qa; r2[cg][sv2*2+1] = qb2;
  __syncthreads();
  if (t < 64){
    float sm = 0.f, sq = 0.f;
    #pragma unroll
    for (int g=0; g<8; g++){ sm += r1[g][t]; sq += r2[g][t]; }
    float mean = sm * 0.0078125f;
    float var  = fmaxf(sq * 0.0078125f - mean*mean, 0.f);
    float inv  = 1.f/(sqrtf(var) + 1e-6f);
    int o = tt*2*S_SP + b*S_SP + sc*64 + t;
    MEAN[o] = mean; INV[o] = inv;   // consumed by k_gather (tt=0)
    mb[t] = mean; ib[t] = inv;
  }
  __syncthreads();
  {
    int sv = sv2*2;
    float m = mb[sv], iv = ib[sv];
    #pragma unroll
    for (int i = 0; i < 16; i += 2){
      int c = cg*16 + i;
      float y0 = G[c]  *(xa[i]  -m)*iv + Bv[c];
      float y1 = G[c+1]*(xa[i+1]-m)*iv + Bv[c+1];
      unsigned short h0 = f2bf(y0), h1 = f2bf(y1);
      unsigned short l0 = f2bf(y0 - bf2f(h0)), l1 = f2bf(y1 - bf2f(h1));
      *(unsigned*)&TH[sv*136 + c] = (unsigned)h0 | ((unsigned)h1 << 16);
      *(unsigned*)&TL[sv*136 + c] = (unsigned)l0 | ((unsigned)l1 << 16);
    }
    sv = sv2*2 + 1;
    m = mb[sv]; iv = ib[sv];
    #pragma unroll
    for (int i = 0; i < 16; i += 2){
      int c = cg*16 + i;
      float y0 = G[c]  *(xb[i]  -m)*iv + Bv[c];
      float y1 = G[c+1]*(xb[i+1]-m)*iv + Bv[c+1];
      unsigned short h0 = f2bf(y0), h1 = f2bf(y1);
      unsigned short l0 = f2bf(y0 - bf2f(h0)), l1 = f2bf(y1 - bf2f(h1));
      *(unsigned*)&TH[sv*136 + c] = (unsigned)h0 | ((unsigned)h1 << 16);
      *(unsigned*)&TL[sv*136 + c] = (unsigned)l0 | ((unsigned)l1 << 16);
    }
  }
  __syncthreads();
  int row = t >> 2, seg = (t & 3) * 32;
  unsigned short* XH = tt ? XTQ_hi : XTC_hi;
  unsigned short* XL = tt ? XTQ_lo : XTC_lo;
  size_t go = ((size_t)b*S_SP + sc*64 + row)*128 + seg;
  #pragma unroll
  for (int k2 = 0; k2 < 4; k2++){
    *(uint4*)(XH + go + k2*8) = *(const uint4*)&TH[row*136 + seg + k2*8];
    *(uint4*)(XL + go + k2*8) = *(const uint4*)&TL[row*136 + seg + k2*8];
  }
}

// ---------------- K2: projection as split-bf16 3-pass MFMA, N=32/wave -------
// D = Ah*Bh + Ah*Bl + Al*Bh ~ fp32-accurate. Wave: M=128 x N=32 (acc 64 VGPR,
// ~2x occupancy vs N=64). Grid 1024 = 4 blocks/CU.
// NOTE: no 2nd launch_bounds arg (r4/r5: clamps VGPR to 64 -> massive spill).
template<int ISK>
__global__ __launch_bounds__(256) void k_proj(
    const unsigned short* __restrict__ XH, const unsigned short* __restrict__ XL,
    const unsigned short* __restrict__ WH, const unsigned short* __restrict__ WL,
    unsigned short* __restrict__ QBF, float* __restrict__ QP,
    float* __restrict__ SCORE){
  __shared__ float qpl[128];
  __shared__ float qacc[128];  // !ISK: block-reduced q_probe
  __shared__ float wacc[64];   // ISK: block-reduced w-axis scores [head*32+w]
  int bx = blockIdx.x;
  int og = bx >> 8, b = (bx >> 7) & 1, stile = bx & 127;
  int t = threadIdx.x, wvi = t >> 6, lane = t & 63;
  int quad = lane >> 4, l15 = lane & 15;
  int sw0 = stile*128 + wvi*32;
  int bh0 = b*8 + og*2;
  if (ISK){
    if (t < 128) qpl[t] = QP[bh0*64 + t];
    if (t < 64) wacc[t] = 0.f;
    __syncthreads();
  } else {
    if (t < 128) qacc[t] = 0.f;  // ordered by the epilogue barrier
  }
  v4f acc[8][2];
  #pragma unroll
  for (int i=0;i<8;i++)
    #pragma unroll
    for (int j=0;j<2;j++) acc[i][j] = (v4f){0.f,0.f,0.f,0.f};
  size_t wrow = ((size_t)(og*128 + l15))*128 + quad*8;
  size_t xrow = ((size_t)b*S_SP + sw0 + l15)*128 + quad*8;
  #pragma unroll 1
  for (int ks=0; ks<4; ks++){
    int ko = ks*32;
    uint4 bhv[2], blv[2], av[8];
    #pragma unroll
    for (int nt=0;nt<2;nt++){
      bhv[nt] = *(const uint4*)(XH + xrow + nt*2048 + ko);
      blv[nt] = *(const uint4*)(XL + xrow + nt*2048 + ko);
    }
    #pragma unroll
    for (int mt=0;mt<8;mt++) av[mt] = *(const uint4*)(WH + wrow + mt*2048 + ko);
    #pragma unroll
    for (int mt=0;mt<8;mt++){
      short8 am = u2s8(av[mt]);
      #pragma unroll
      for (int nt=0;nt<2;nt++)
        acc[mt][nt] = __builtin_amdgcn_mfma_f32_16x16x32_bf16(am, u2s8(bhv[nt]), acc[mt][nt], 0, 0, 0);
      #pragma unroll
      for (int nt=0;nt<2;nt++)
        acc[mt][nt] = __builtin_amdgcn_mfma_f32_16x16x32_bf16(am, u2s8(blv[nt]), acc[mt][nt], 0, 0, 0);
    }
    #pragma unroll
    for (int mt=0;mt<8;mt++){
      short8 am = u2s8(*(const uint4*)(WL + wrow + mt*2048 + ko));
      #pragma unroll
      for (int nt=0;nt<2;nt++)
        acc[mt][nt] = __builtin_amdgcn_mfma_f32_16x16x32_bf16(am, u2s8(bhv[nt]), acc[mt][nt], 0, 0, 0);
    }
  }
  // per-head l2norm inverses (per spatial col): in-lane + quad shfl reduce
  float inv0[2], inv1[2];
  #pragma unroll
  for (int nt=0;nt<2;nt++){
    float p0 = 0.f, p1 = 0.f;
    #pragma unroll
    for (int mt=0;mt<4;mt++)
      #pragma unroll
      for (int r=0;r<4;r++){
        p0 += acc[mt][nt][r]*acc[mt][nt][r];
        p1 += acc[mt+4][nt][r]*acc[mt+4][nt][r];
      }
    p0 += __shfl_xor(p0,16,64); p0 += __shfl_xor(p0,32,64);
    p1 += __shfl_xor(p1,16,64); p1 += __shfl_xor(p1,32,64);
    inv0[nt] = 1.f/fmaxf(sqrtf(p0),1e-12f);
    inv1[nt] = 1.f/fmaxf(sqrtf(p1),1e-12f);
  }
  if (!ISK){
    #pragma unroll
    for (int mt=0;mt<8;mt++)
      #pragma unroll
      for (int nt=0;nt<2;nt++){
        float iv = (mt<4) ? inv0[nt] : inv1[nt];
        #pragma unroll
        for (int r=0;r<4;r++) acc[mt][nt][r] *= iv;
      }
    // QBF: [bh][s][64c] bf16 (layout k_attn expects)
    #pragma unroll
    for (int mt=0;mt<8;mt++){
      int bh = bh0 + (mt>>2);
      #pragma unroll
      for (int nt=0;nt<2;nt++){
        int s = sw0 + nt*16 + l15;
        uint2 wv;
        wv.x = pk2(acc[mt][nt][0], acc[mt][nt][1]);
        wv.y = pk2(acc[mt][nt][2], acc[mt][nt][3]);
        *(uint2*)(QBF + ((size_t)bh*S_SP + s)*64 + (mt&3)*16 + quad*4) = wv;
      }
    }
    __syncthreads();  // orders qacc zeroing before LDS atomics
    #pragma unroll
    for (int mt=0;mt<8;mt++){
      #pragma unroll
      for (int r=0;r<4;r++){
        float v = acc[mt][0][r]+acc[mt][1][r];
        v += __shfl_xor(v,1,64); v += __shfl_xor(v,2,64);
        v += __shfl_xor(v,4,64); v += __shfl_xor(v,8,64);
        if (l15 == 0)
          atomicAdd(&qacc[(mt>>2)*64 + (mt&3)*16 + quad*4 + r], v);
      }
    }
    __syncthreads();
    if (t < 128) atomicAdd(QP + bh0*64 + t, qacc[t]);
  } else {
    // val(s, head) = inv_s * sum_c qp_c * |k_cs|; fold onto d/h/w axis slots.
    // s = stile*128 + wvi*32 + nt*16 + l15:
    //   w = nt*16+l15 ; h = (stile&7)*4 + wvi (per-wave const) ; d = stile>>3
    float v0[2] = {0.f,0.f}, v1[2] = {0.f,0.f};
    #pragma unroll
    for (int mt=0;mt<8;mt++){
      #pragma unroll
      for (int r=0;r<4;r++){
        float w = qpl[mt*16 + quad*4 + r];
        #pragma unroll
        for (int nt=0;nt<2;nt++){
          float av = fabsf(acc[mt][nt][r]) * w;
          if (mt < 4) v0[nt] += av; else v1[nt] += av;
        }
      }
    }
    #pragma unroll
    for (int nt=0;nt<2;nt++){
      v0[nt] += __shfl_xor(v0[nt],16,64); v0[nt] += __shfl_xor(v0[nt],32,64);
      v1[nt] += __shfl_xor(v1[nt],16,64); v1[nt] += __shfl_xor(v1[nt],32,64);
      v0[nt] *= inv0[nt]; v1[nt] *= inv1[nt];
    }
    if (lane < 16){ // block-level LDS reduce for the hot w-axis slots
      atomicAdd(&wacc[l15],      v0[0]);
      atomicAdd(&wacc[16+l15],   v0[1]);
      atomicAdd(&wacc[32+l15],   v1[0]);
      atomicAdd(&wacc[48+l15],   v1[1]);
    }
    float h0 = v0[0] + v0[1], h1 = v1[0] + v1[1];
    #pragma unroll
    for (int mm=1; mm<16; mm<<=1){
      h0 += __shfl_xor(h0,mm,64); h1 += __shfl_xor(h1,mm,64);
    }
    if (lane == 0){
      int hh = 16 + (stile&7)*4 + wvi;
      int dd = stile >> 3;
      atomicAdd(SCORE + bh0*80 + hh, h0);
      atomicAdd(SCORE + (bh0+1)*80 + hh, h1);
      atomicAdd(SCORE + bh0*80 + dd, h0);
      atomicAdd(SCORE + (bh0+1)*80 + dd, h1);
    }
    __syncthreads();
    if (t < 64) atomicAdd(SCORE + (bh0 + (t>>5))*80 + 48 + (t&31), wacc[t]);
  }
}

// ---------------- K4: topk (inlined, wave 0) + gather-recompute ------------
__global__ __launch_bounds__(256) void k_gather(const float* __restrict__ ctx,
    const float* __restrict__ wkv, const float* __restrict__ ctx_g,
    const float* __restrict__ ctx_b, const float* __restrict__ MEAN,
    const float* __restrict__ INV, const float* __restrict__ SCORE,
    unsigned short* __restrict__ KG, unsigned short* __restrict__ VGT){
  __shared__ float wlds[64*129];
  __shared__ float xln[32*128];
  __shared__ float scb[80];
  __shared__ int sidx[24];
  int bx = blockIdx.x;
  int bh = bx >> 5, jc = (bx >> 1) & 15, type = bx & 1;
  int head = bh & 7, b = bh >> 3;
  int t = threadIdx.x;
  if (t < 80) scb[t] = SCORE[bh*80 + t];
  {
    int oc = t>>2, ks = (t&3)*32;
    const float* wr = wkv + ((size_t)(type*512 + head*64 + oc))*128 + ks;
    #pragma unroll 8
    for (int i=0;i<32;i++) wlds[oc*129 + ks + i] = wr[i];
  }
  __syncthreads();
  if (t < 64){ // wave 0: butterfly top-8 per axis (ties -> lowest idx)
    #pragma unroll 1
    for (int a=0;a<3;a++){
      int n = a ? 32 : 16;
      int off = (a==0) ? 0 : (a==1 ? 16 : 48);
      float v = (t < n) ? scb[off+t] : -3.4e38f;
      #pragma unroll 1
      for (int it=0; it<8; it++){
        float bv = v; int bi = t;
        #pragma unroll
        for (int mm=1; mm<32; mm<<=1){
          float ov = __shfl_xor(bv, mm, 64);
          int oi = __shfl_xor(bi, mm, 64);
          if (ov > bv || (ov == bv && oi < bi)){ bv = ov; bi = oi; }
        }
        if (t == bi) v = -3.4e38f;
        if (t == 0) sidx[a*8+it] = bi;
      }
    }
  }
  __syncthreads();
  {
    int jl = t>>3, seg = (t&7)*16;
    int jj = jc*32 + jl;
    int dsel = sidx[jj>>6], hsel = sidx[8 + ((jj>>3)&7)], wsel = sidx[16 + (jj&7)];
    int sj = dsel*1024 + hsel*32 + wsel;
    float mn = MEAN[b*S_SP + sj];
    float iv = INV[b*S_SP + sj];
    #pragma unroll
    for (int i=0;i<16;i++){
      int cc = seg + i;
      float raw = ctx[((size_t)(b*128 + cc))*S_SP + sj];
      xln[jl*128 + cc] = ctx_g[cc]*(raw - mn)*iv + ctx_b[cc];
    }
  }
  __syncthreads();
  int c = t & 63, jg = t >> 6;
  float accv[8] = {};
  #pragma unroll 4
  for (int k=0;k<128;k++){
    float wv = wlds[c*129 + k];
    #pragma unroll
    for (int m=0;m<8;m++) accv[m] += wv * xln[(jg + 4*m)*128 + k];
  }
  #pragma unroll
  for (int m=0;m<8;m++){
    int jj = jc*32 + jg + 4*m;
    float a = accv[m];
    if (type == 0){
      float sq = a*a;
      #pragma unroll
      for (int mm=32; mm; mm>>=1) sq += __shfl_xor(sq, mm, 64);
      float rn = 1.f/fmaxf(sqrtf(sq), 1e-12f);
      KG[((size_t)bh*NKV + jj)*64 + c] = f2bf(a*rn);
    } else {
      VGT[((size_t)bh*64 + c)*NKV + jj] = f2bf(a);
    }
  }
}

// ---------------- K5: attention, async-dbuf, merged single dispatch ---------
// 1024 blocks x 4 waves -> 3 blocks/CU (LDS 51200). pst stride 36 shorts:
// bank-conflict-free (r10 measured: SQ_LDS_BANK_CONFLICT = 0).
// |sim|<=1 (l2-normed q,k) => softmax == exp(s-1)/sum: no max pass.
__global__ __launch_bounds__(256) void k_attn(const unsigned short* __restrict__ QBF,
    const unsigned short* __restrict__ KG, const unsigned short* __restrict__ VGT,
    unsigned short* __restrict__ AOUT){
  __shared__ __align__(16) unsigned short kst[2][64*64];  // K chunk [j][c] swz
  __shared__ __align__(16) unsigned short vst[2][64*64];  // V chunk [c][j] swz
  __shared__ __align__(16) unsigned short pst[4][64*36];  // per-wave P, stride 36
  int bx = blockIdx.x;
  int bh = bx >> 6, qb = bx & 63;
  int t = threadIdx.x;
  int wvi = t >> 6, lane = t & 63;
  int quad = lane >> 4, l15 = lane & 15;
  int r3 = lane >> 3, s3 = lane & 7;
  int q0 = qb*256 + wvi*64;
  const unsigned short* kgb = KG + (size_t)bh*NKV*64;
  const unsigned short* vgb = VGT + (size_t)bh*64*NKV;
  // Q fragments as B-operand: n=q=l15, k=c=quad*8+i
  short8 bq[4][2];
  #pragma unroll
  for (int qt=0; qt<4; qt++){
    const unsigned short* qp_ = QBF + ((size_t)bh*S_SP + q0 + qt*16 + l15)*64 + quad*8;
    union { uint4 u; short8 s; } u0, u1;
    u0.u = *(const uint4*)(qp_);
    u1.u = *(const uint4*)(qp_ + 32);
    bq[qt][0] = u0.s; bq[qt][1] = u1.s;
  }
  v4f oacc[4][4]; // [ct][qt]: O^T tile: col=q=l15, row=c=ct*16+quad*4+r
  #pragma unroll
  for (int i=0;i<4;i++)
    #pragma unroll
    for (int j=0;j<4;j++) oacc[i][j] = (v4f){0.f,0.f,0.f,0.f};
  float lsum[4] = {0.f,0.f,0.f,0.f};
  unsigned short* pw = pst[wvi];
  int swz = (s3 ^ r3) << 3;   // pre-swizzled source block (8 shorts)
  // prologue: stage chunk 0 -> buf 0 (each wave: 16 K rows + 16 V rows)
  #pragma unroll
  for (int i=0;i<2;i++){
    int rowb = wvi*16 + i*8;
    gll16(kgb + ((size_t)(rowb + r3))*64 + swz,  &kst[0][rowb*64]);
    gll16(vgb + ((size_t)(rowb + r3))*NKV + swz, &vst[0][rowb*64]);
  }
  __syncthreads();
  #pragma unroll 1
  for (int ch=0; ch<8; ch++){
    int cur = ch & 1;
    if (ch < 7){ // async prefetch next chunk into the other buffer
      #pragma unroll
      for (int i=0;i<2;i++){
        int rowb = wvi*16 + i*8;
        gll16(kgb + ((size_t)((ch+1)*64 + rowb + r3))*64 + swz, &kst[cur^1][rowb*64]);
        gll16(vgb + ((size_t)(rowb + r3))*NKV + (ch+1)*64 + swz, &vst[cur^1][rowb*64]);
      }
    }
    const unsigned short* kb = kst[cur];
    const unsigned short* vb = vst[cur];
    #pragma unroll
    for (int sub=0; sub<2; sub++){ // 32 j per sub
      #pragma unroll
      for (int j2=0; j2<2; j2++){
        int jr = (sub*2 + j2)*16 + l15;
        int sk = jr & 7;
        union { uint4 u; short8 s; } a0, a1;
        a0.u = *(const uint4*)(kb + jr*64 + ((quad^sk)*8));
        a1.u = *(const uint4*)(kb + jr*64 + (((quad+4)^sk)*8));
        v4f s4[4];
        __builtin_amdgcn_s_setprio(1);
        #pragma unroll
        for (int qt=0; qt<4; qt++){
          v4f z = {0.f,0.f,0.f,0.f};
          z = __builtin_amdgcn_mfma_f32_16x16x32_bf16(a0.s, bq[qt][0], z, 0, 0, 0);
          z = __builtin_amdgcn_mfma_f32_16x16x32_bf16(a1.s, bq[qt][1], z, 0, 0, 0);
          s4[qt] = z;
        }
        __builtin_amdgcn_s_setprio(0);
        #pragma unroll
        for (int qt=0; qt<4; qt++){
          v4f p;
          #pragma unroll
          for (int r=0;r<4;r++) p[r] = __expf(s4[qt][r] - 1.0f);
          lsum[qt] += p[0]+p[1]+p[2]+p[3];
          uint2 wv;
          wv.x = pk2(p[0], p[1]);
          wv.y = pk2(p[2], p[3]);
          int qr = qt*16 + l15;
          *(uint2*)&pw[qr*36 + j2*16 + quad*4] = wv;  // plain P[qr][j]
        }
      }
      // PV: O^T += V^T(64c x 32j) . P^T(32j x 64q)
      short8 bp[4];
      #pragma unroll
      for (int qt=0; qt<4; qt++){
        int qr = qt*16 + l15;
        union { uint4 u; short8 s; } ub;
        ub.u = *(const uint4*)&pw[qr*36 + quad*8];
        bp[qt] = ub.s;
      }
      #pragma unroll
      for (int ct=0; ct<4; ct++){
        int cr = ct*16 + l15;
        union { uint4 u; short8 s; } av;
        av.u = *(const uint4*)(vb + cr*64 + (((sub*4+quad)^(cr&7))*8));
        __builtin_amdgcn_s_setprio(1);
        #pragma unroll
        for (int qt=0; qt<4; qt++)
          oacc[ct][qt] = __builtin_amdgcn_mfma_f32_16x16x32_bf16(av.s, bp[qt], oacc[ct][qt], 0, 0, 0);
        __builtin_amdgcn_s_setprio(0);
      }
    }
    __syncthreads();  // drains vmcnt: prefetched chunk landed; LDS reads done
  }
  float rl[4];
  #pragma unroll
  for (int qt=0; qt<4; qt++){
    float l = lsum[qt];
    l += __shfl_xor(l, 16, 64);
    l += __shfl_xor(l, 32, 64);
    rl[qt] = 1.f/l;
  }
  #pragma unroll
  for (int qt=0; qt<4; qt++){
    #pragma unroll
    for (int ct=0; ct<4; ct++){
      v4f o = oacc[ct][qt];
      uint2 wv;
      wv.x = pk2(o[0]*rl[qt], o[1]*rl[qt]);
      wv.y = pk2(o[2]*rl[qt], o[3]*rl[qt]);
      *(uint2*)(AOUT + ((size_t)bh*S_SP + q0 + qt*16 + l15)*64 + ct*16 + quad*4) = wv;
    }
  }
}

// ---------------- K6: out-projection, double-buffered W (17 barriers vs 32) -
__global__ __launch_bounds__(256) void k_out(const unsigned short* __restrict__ AOUT,
    const float* __restrict__ wout, const float* __restrict__ out_g,
    const float* __restrict__ out_b, const float* __restrict__ gamma,
    const float* __restrict__ qsrc, float* __restrict__ OUT){
  __shared__ __align__(16) unsigned short wl[2][128*40];
  __shared__ float lnp[4][2][64];
  __shared__ float mbuf[64], sbuf[64], ogl[128], obl[128];
  int bx = blockIdx.x; int b = bx>>8; int stile = bx&255; int s0 = stile*64;
  int t = threadIdx.x; int w = t>>6; int lane = t&63;
  int q = lane>>4; int l15 = lane&15;
  if (t < 128){ ogl[t] = out_g[t]; obl[t] = out_b[t]; }
  int cst = t>>1, kbs = (t&1)*16;
  v4f acc[2][4];
  #pragma unroll
  for (int i=0;i<2;i++)
    #pragma unroll
    for (int j=0;j<4;j++) acc[i][j] = (v4f){0.f,0.f,0.f,0.f};
  { // prologue: stage kt=0 into buf 0
    const float* wr = wout + (size_t)cst*512 + kbs;
    v4f a0 = *(const v4f*)wr, a1 = *(const v4f*)(wr+4);
    v4f a2 = *(const v4f*)(wr+8), a3 = *(const v4f*)(wr+12);
    uint4 u0, u1;
    u0.x = pk2(a0[0], a0[1]); u0.y = pk2(a0[2], a0[3]);
    u0.z = pk2(a1[0], a1[1]); u0.w = pk2(a1[2], a1[3]);
    u1.x = pk2(a2[0], a2[1]); u1.y = pk2(a2[2], a2[3]);
    u1.z = pk2(a3[0], a3[1]); u1.w = pk2(a3[2], a3[3]);
    *(uint4*)&wl[0][cst*40+kbs]   = u0;
    *(uint4*)&wl[0][cst*40+kbs+8] = u1;
  }
  __syncthreads();
  for (int kt=0; kt<16; kt++){
    if (kt < 15){ // stage kt+1 into the other buffer (no barrier needed here)
      const float* wr = wout + (size_t)cst*512 + (kt+1)*32 + kbs;
      v4f a0 = *(const v4f*)wr, a1 = *(const v4f*)(wr+4);
      v4f a2 = *(const v4f*)(wr+8), a3 = *(const v4f*)(wr+12);
      uint4 u0, u1;
      u0.x = pk2(a0[0], a0[1]); u0.y = pk2(a0[2], a0[3]);
      u0.z = pk2(a1[0], a1[1]); u0.w = pk2(a1[2], a1[3]);
      u1.x = pk2(a2[0], a2[1]); u1.y = pk2(a2[2], a2[3]);
      u1.z = pk2(a3[0], a3[1]); u1.w = pk2(a3[2], a3[3]);
      *(uint4*)&wl[(kt+1)&1][cst*40+kbs]   = u0;
      *(uint4*)&wl[(kt+1)&1][cst*40+kbs+8] = u1;
    }
    const unsigned short* wb = wl[kt&1];
    short8 af[2];
    #pragma unroll
    for (int mt=0;mt<2;mt++){
      union { uint4 u; short8 s; } ua;
      ua.u = *(const uint4*)&wb[(w*32+mt*16+l15)*40 + q*8];
      af[mt] = ua.s;
    }
    int head = kt>>1; int cc0 = (kt&1)*32 + q*8;
    const unsigned short* bp = AOUT + ((size_t)((b*8+head)*S_SP + s0 + l15))*64 + cc0;
    #pragma unroll
    for (int nt=0;nt<4;nt++){
      union { uint4 u; short8 s; } ub;
      ub.u = *(const uint4*)(bp + (size_t)nt*16*64);
      #pragma unroll
      for (int mt=0;mt<2;mt++)
        acc[mt][nt] = __builtin_amdgcn_mfma_f32_16x16x32_bf16(af[mt], ub.s, acc[mt][nt], 0, 0, 0);
    }
    __syncthreads();
  }
  #pragma unroll
  for (int nt=0;nt<4;nt++){
    float p1 = 0.f, p2 = 0.f;
    #pragma unroll
    for (int mt=0;mt<2;mt++)
      #pragma unroll
      for (int r=0;r<4;r++){ float v = acc[mt][nt][r]; p1 += v; p2 += v*v; }
    p1 += __shfl_xor(p1,16,64); p1 += __shfl_xor(p1,32,64);
    p2 += __shfl_xor(p2,16,64); p2 += __shfl_xor(p2,32,64);
    if (q == 0){ lnp[w][0][nt*16+l15] = p1; lnp[w][1][nt*16+l15] = p2; }
  }
  __syncthreads();
  if (t < 64){
    float m = (lnp[0][0][t]+lnp[1][0][t]+lnp[2][0][t]+lnp[3][0][t]) * 0.0078125f;
    float qq = (lnp[0][1][t]+lnp[1][1][t]+lnp[2][1][t]+lnp[3][1][t]) * 0.0078125f;
    float var = fmaxf(qq - m*m, 0.f);
    mbuf[t] = m;
    sbuf[t] = 1.f/(sqrtf(var) + 1e-6f);
  }
  __syncthreads();
  float gs = gamma[0];
  #pragma unroll
  for (int nt=0;nt<4;nt++){
    int sl = nt*16 + l15;
    float mm = mbuf[sl], ssc = sbuf[sl];
    #pragma unroll
    for (int mt=0;mt<2;mt++){
      #pragma unroll
      for (int r=0;r<4;r++){
        int c = w*32 + mt*16 + q*4 + r;
        size_t adr = ((size_t)(b*128+c))*S_SP + s0 + sl;
        float yn = (acc[mt][nt][r]-mm)*ssc;
        OUT[adr] = gs*(ogl[c]*yn + obl[c]) + qsrc[adr];
      }
    }
  }
}

extern "C" void kernel_launch(void* const* d_in, const int* in_sizes, int n_in,
                              void* d_out, int out_size, void* d_ws, size_t ws_size,
                              hipStream_t stream){
  const float* qsrc  = (const float*)d_in[0];
  const float* ctx   = (const float*)d_in[1];
  const float* wq    = (const float*)d_in[2];
  const float* wkv   = (const float*)d_in[3];
  const float* wout  = (const float*)d_in[4];
  const float* ctx_g = (const float*)d_in[5];
  const float* ctx_b = (const float*)d_in[6];
  const float* qs_g  = (const float*)d_in[7];
  const float* qs_b  = (const float*)d_in[8];
  const float* out_g = (const float*)d_in[9];
  const float* out_b = (const float*)d_in[10];
  const float* gamma = (const float*)d_in[11];
  float* OUT = (float*)d_out;
  char* ws = (char*)d_ws;
  float* QP    = (float*)(ws);
  float* SCORE = (float*)(ws + 4096);
  float* MEAN  = (float*)(ws + 16384);
  float* INV   = (float*)(ws + 278528);
  unsigned short* QBF  = (unsigned short*)(ws + 544768);
  unsigned short* KG   = (unsigned short*)(ws + 34099200);
  unsigned short* VGT  = (unsigned short*)(ws + 35147776);
  unsigned short* AOUT = (unsigned short*)(ws + 36196352);
  // W hi/lo alias the KG region (dead until k_gather runs)
  unsigned short* WQh = (unsigned short*)(ws + 34099200);
  unsigned short* WQl = (unsigned short*)(ws + 34230272);
  unsigned short* WKh = (unsigned short*)(ws + 34361344);
  unsigned short* WKl = (unsigned short*)(ws + 34492416);
  // XT hi/lo alias the AOUT region (dead until k_attn runs); ends at 69750784
  unsigned short* XTQh = (unsigned short*)(ws + 36196352);
  unsigned short* XTQl = (unsigned short*)(ws + 44584960);
  unsigned short* XTCh = (unsigned short*)(ws + 52973568);
  unsigned short* XTCl = (unsigned short*)(ws + 61362176);

  hipMemsetAsync(ws, 0, 9216, stream); // QP + SCORE
  k_stats<<<1088, 256, 0, stream>>>(ctx, qsrc, ctx_g, ctx_b, qs_g, qs_b, wq, wkv,
                                    MEAN, INV, XTCh, XTCl, XTQh, XTQl,
                                    WQh, WQl, WKh, WKl);
  k_proj<0><<<1024, 256, 0, stream>>>(XTQh, XTQl, WQh, WQl, QBF, QP, SCORE);
  k_proj<1><<<1024, 256, 0, stream>>>(XTCh, XTCl, WKh, WKl, QBF, QP, SCORE);
  k_gather<<<512, 256, 0, stream>>>(ctx, wkv, ctx_g, ctx_b, MEAN, INV, SCORE, KG, VGT);
  k_attn<<<1024, 256, 0, stream>>>(QBF, KG, VGT, AOUT);
  k_out<<<512, 256, 0, stream>>>(AOUT, wout, out_g, out_b, gamma, qsrc, OUT);
}

// Round 16
// 335.208 us; speedup vs baseline: 1.0783x; 1.0783x over previous
//
#include <hip/hip_runtime.h>
#include <hip/hip_bf16.h>

#define S_SP 16384
#define NKV 512

typedef short short8 __attribute__((ext_vector_type(8)));
typedef float v4f   __attribute__((ext_vector_type(4)));

__device__ __forceinline__ unsigned short f2bf(float x){
  union { float f; unsigned u; } v; v.f = x;
  unsigned r = v.u + 0x7FFFu + ((v.u >> 16) & 1u);
  return (unsigned short)(r >> 16);
}
__device__ __forceinline__ float bf2f(unsigned short h){
  union { unsigned u; float f; } v; v.u = ((unsigned)h) << 16; return v.f;
}

#if defined(__has_builtin)
#if __has_builtin(__builtin_amdgcn_cvt_pk_bf16_f32)
#define HAVE_PKBF 1
#endif
#endif

__device__ __forceinline__ unsigned pk2(float a, float b){
#ifdef HAVE_PKBF
  typedef __bf16 bf16x2 __attribute__((ext_vector_type(2)));
  union { bf16x2 v; unsigned u; } r;
  r.v = __builtin_amdgcn_cvt_pk_bf16_f32(a, b);
  return r.u;
#else
  return (unsigned)f2bf(a) | ((unsigned)f2bf(b) << 16);
#endif
}

__device__ __forceinline__ short8 u2s8(uint4 u){
  union { uint4 u; short8 s; } x; x.u = u; return x.s;
}

// async global->LDS, 16B/lane; LDS dest = wave-uniform base + lane*16
__device__ __forceinline__ void gll16(const unsigned short* g, unsigned short* l){
  __builtin_amdgcn_global_load_lds(
    (const __attribute__((address_space(1))) unsigned int*)g,
    (__attribute__((address_space(3))) unsigned int*)l, 16, 0, 0);
}

// ---------------- K1: channel-LN stats + pre-LN'd transposed bf16 hi/lo copy
// Blocks [0,1024): stats + XT emit. Blocks [1024,1088): W hi/lo split.
__global__ __launch_bounds__(256) void k_stats(const float* __restrict__ ctx,
                                               const float* __restrict__ qs,
                                               const float* __restrict__ ctx_g,
                                               const float* __restrict__ ctx_b,
                                               const float* __restrict__ qs_g,
                                               const float* __restrict__ qs_b,
                                               const float* __restrict__ wq,
                                               const float* __restrict__ wkv,
                                               float* __restrict__ MEAN,
                                               float* __restrict__ INV,
                                               unsigned short* __restrict__ XTC_hi,
                                               unsigned short* __restrict__ XTC_lo,
                                               unsigned short* __restrict__ XTQ_hi,
                                               unsigned short* __restrict__ XTQ_lo,
                                               unsigned short* __restrict__ WQh,
                                               unsigned short* __restrict__ WQl,
                                               unsigned short* __restrict__ WKh,
                                               unsigned short* __restrict__ WKl){
  __shared__ float r1[4][64];
  __shared__ float r2[4][64];
  __shared__ float mb[64], ib[64];
  __shared__ __align__(16) unsigned short TH[64*136];
  __shared__ __align__(16) unsigned short TL[64*136];
  int bx = blockIdx.x;
  int t = threadIdx.x;
  if (bx >= 1024){ // W hi/lo split: wq (512x128) then wkv K-half (512x128)
    int wb = bx - 1024;
    int isK = wb >> 5;
    size_t i8 = ((size_t)(wb & 31)*256 + t)*8;
    const float* srcw = isK ? wkv : wq;
    unsigned short* dh = isK ? WKh : WQh;
    unsigned short* dl = isK ? WKl : WQl;
    v4f a  = *(const v4f*)(srcw + i8);
    v4f b2 = *(const v4f*)(srcw + i8 + 4);
    unsigned short h[8], l[8];
    #pragma unroll
    for (int i=0;i<4;i++){
      h[i]   = f2bf(a[i]);  l[i]   = f2bf(a[i]  - bf2f(h[i]));
      h[i+4] = f2bf(b2[i]); l[i+4] = f2bf(b2[i] - bf2f(h[i+4]));
    }
    uint4 uh, ul;
    uh.x = (unsigned)h[0] | ((unsigned)h[1]<<16);
    uh.y = (unsigned)h[2] | ((unsigned)h[3]<<16);
    uh.z = (unsigned)h[4] | ((unsigned)h[5]<<16);
    uh.w = (unsigned)h[6] | ((unsigned)h[7]<<16);
    ul.x = (unsigned)l[0] | ((unsigned)l[1]<<16);
    ul.y = (unsigned)l[2] | ((unsigned)l[3]<<16);
    ul.z = (unsigned)l[4] | ((unsigned)l[5]<<16);
    ul.w = (unsigned)l[6] | ((unsigned)l[7]<<16);
    *(uint4*)(dh + i8) = uh;
    *(uint4*)(dl + i8) = ul;
    return;
  }
  int tt = bx >> 9; int b = (bx >> 8) & 1; int sc = bx & 255;
  int sv = t & 63, cg = t >> 6;
  int s = sc*64 + sv;
  const float* src = (tt ? qs : ctx) + ((size_t)b*128 + cg*32)*S_SP + s;
  const float* G  = tt ? qs_g : ctx_g;
  const float* Bv = tt ? qs_b : ctx_b;
  float xv[32];
  float sum = 0.f, ss = 0.f;
  #pragma unroll
  for (int c = 0; c < 32; c++){
    float v = src[(size_t)c*S_SP];
    xv[c] = v;
    sum += v; ss += v*v;
  }
  r1[cg][sv] = sum; r2[cg][sv] = ss;
  __syncthreads();
  if (t < 64){
    float sm = r1[0][t]+r1[1][t]+r1[2][t]+r1[3][t];
    float sq = r2[0][t]+r2[1][t]+r2[2][t]+r2[3][t];
    float mean = sm * 0.0078125f;
    float var  = fmaxf(sq * 0.0078125f - mean*mean, 0.f);
    float inv  = 1.f/(sqrtf(var) + 1e-6f);
    int o = tt*2*S_SP + b*S_SP + sc*64 + t;
    MEAN[o] = mean; INV[o] = inv;   // consumed by k_gather (tt=0)
    mb[t] = mean; ib[t] = inv;
  }
  __syncthreads();
  float m = mb[sv], iv = ib[sv];
  #pragma unroll
  for (int i = 0; i < 32; i += 2){
    int c = cg*32 + i;
    float y0 = G[c]  *(xv[i]  -m)*iv + Bv[c];
    float y1 = G[c+1]*(xv[i+1]-m)*iv + Bv[c+1];
    unsigned short h0 = f2bf(y0), h1 = f2bf(y1);
    unsigned short l0 = f2bf(y0 - bf2f(h0)), l1 = f2bf(y1 - bf2f(h1));
    *(unsigned*)&TH[sv*136 + c] = (unsigned)h0 | ((unsigned)h1 << 16);
    *(unsigned*)&TL[sv*136 + c] = (unsigned)l0 | ((unsigned)l1 << 16);
  }
  __syncthreads();
  int row = t >> 2, seg = (t & 3) * 32;
  unsigned short* XH = tt ? XTQ_hi : XTC_hi;
  unsigned short* XL = tt ? XTQ_lo : XTC_lo;
  size_t go = ((size_t)b*S_SP + sc*64 + row)*128 + seg;
  #pragma unroll
  for (int k2 = 0; k2 < 4; k2++){
    *(uint4*)(XH + go + k2*8) = *(const uint4*)&TH[row*136 + seg + k2*8];
    *(uint4*)(XL + go + k2*8) = *(const uint4*)&TL[row*136 + seg + k2*8];
  }
}

// ---------------- K2: projection as split-bf16 3-pass MFMA (r7 version) -----
// D = Ah*Bh + Ah*Bl + Al*Bh  ~  fp32-accurate (missing Al*Bl ~2^-18).
// NOTE: no 2nd launch_bounds arg (r4/r5: clamps VGPR to 64 -> massive spill).
// N=64/wave (r11's N=32 regressed: halved arithmetic intensity).
template<int ISK>
__global__ __launch_bounds__(256) void k_proj(
    const unsigned short* __restrict__ XH, const unsigned short* __restrict__ XL,
    const unsigned short* __restrict__ WH, const unsigned short* __restrict__ WL,
    unsigned short* __restrict__ QBF, float* __restrict__ QP,
    float* __restrict__ SCORE){
  __shared__ float qpl[128];
  __shared__ float qacc[128];  // !ISK: block-reduced q_probe
  __shared__ float wacc[64];   // ISK: block-reduced w-axis scores [head*32+w]
  int bx = blockIdx.x;
  int og = bx >> 7, b = (bx >> 6) & 1, stile = bx & 63;
  int t = threadIdx.x, wvi = t >> 6, lane = t & 63;
  int quad = lane >> 4, l15 = lane & 15;
  int sw0 = stile*256 + wvi*64;
  int bh0 = b*8 + og*2;
  if (ISK){
    if (t < 128) qpl[t] = QP[bh0*64 + t];
    if (t < 64) wacc[t] = 0.f;
    __syncthreads();
  } else {
    if (t < 128) qacc[t] = 0.f;  // ordered by the epilogue barrier
  }
  v4f acc[8][4];
  #pragma unroll
  for (int i=0;i<8;i++)
    #pragma unroll
    for (int j=0;j<4;j++) acc[i][j] = (v4f){0.f,0.f,0.f,0.f};
  size_t wrow = ((size_t)(og*128 + l15))*128 + quad*8;
  size_t xrow = ((size_t)b*S_SP + sw0 + l15)*128 + quad*8;
  #pragma unroll 1
  for (int ks=0; ks<4; ks++){
    int ko = ks*32;
    uint4 bhv[4], blv[4], av[8];
    #pragma unroll
    for (int nt=0;nt<4;nt++){
      bhv[nt] = *(const uint4*)(XH + xrow + nt*2048 + ko);
      blv[nt] = *(const uint4*)(XL + xrow + nt*2048 + ko);
    }
    #pragma unroll
    for (int mt=0;mt<8;mt++) av[mt] = *(const uint4*)(WH + wrow + mt*2048 + ko);
    #pragma unroll
    for (int mt=0;mt<8;mt++){
      short8 am = u2s8(av[mt]);
      #pragma unroll
      for (int nt=0;nt<4;nt++)
        acc[mt][nt] = __builtin_amdgcn_mfma_f32_16x16x32_bf16(am, u2s8(bhv[nt]), acc[mt][nt], 0, 0, 0);
      #pragma unroll
      for (int nt=0;nt<4;nt++)
        acc[mt][nt] = __builtin_amdgcn_mfma_f32_16x16x32_bf16(am, u2s8(blv[nt]), acc[mt][nt], 0, 0, 0);
    }
    #pragma unroll
    for (int mt=0;mt<8;mt++){
      short8 am = u2s8(*(const uint4*)(WL + wrow + mt*2048 + ko));
      #pragma unroll
      for (int nt=0;nt<4;nt++)
        acc[mt][nt] = __builtin_amdgcn_mfma_f32_16x16x32_bf16(am, u2s8(bhv[nt]), acc[mt][nt], 0, 0, 0);
    }
  }
  // per-head l2norm inverses (per spatial col): in-lane + quad shfl reduce
  float inv0[4], inv1[4];
  #pragma unroll
  for (int nt=0;nt<4;nt++){
    float p0 = 0.f, p1 = 0.f;
    #pragma unroll
    for (int mt=0;mt<4;mt++)
      #pragma unroll
      for (int r=0;r<4;r++){
        p0 += acc[mt][nt][r]*acc[mt][nt][r];
        p1 += acc[mt+4][nt][r]*acc[mt+4][nt][r];
      }
    p0 += __shfl_xor(p0,16,64); p0 += __shfl_xor(p0,32,64);
    p1 += __shfl_xor(p1,16,64); p1 += __shfl_xor(p1,32,64);
    inv0[nt] = 1.f/fmaxf(sqrtf(p0),1e-12f);
    inv1[nt] = 1.f/fmaxf(sqrtf(p1),1e-12f);
  }
  if (!ISK){
    #pragma unroll
    for (int mt=0;mt<8;mt++)
      #pragma unroll
      for (int nt=0;nt<4;nt++){
        float iv = (mt<4) ? inv0[nt] : inv1[nt];
        #pragma unroll
        for (int r=0;r<4;r++) acc[mt][nt][r] *= iv;
      }
    // QBF: [bh][s][64c] bf16 (layout k_attn expects)
    #pragma unroll
    for (int mt=0;mt<8;mt++){
      int bh = bh0 + (mt>>2);
      #pragma unroll
      for (int nt=0;nt<4;nt++){
        int s = sw0 + nt*16 + l15;
        uint2 wv;
        wv.x = pk2(acc[mt][nt][0], acc[mt][nt][1]);
        wv.y = pk2(acc[mt][nt][2], acc[mt][nt][3]);
        *(uint2*)(QBF + ((size_t)bh*S_SP + s)*64 + (mt&3)*16 + quad*4) = wv;
      }
    }
    __syncthreads();  // orders qacc zeroing before LDS atomics
    #pragma unroll
    for (int mt=0;mt<8;mt++){
      #pragma unroll
      for (int r=0;r<4;r++){
        float v = acc[mt][0][r]+acc[mt][1][r]+acc[mt][2][r]+acc[mt][3][r];
        v += __shfl_xor(v,1,64); v += __shfl_xor(v,2,64);
        v += __shfl_xor(v,4,64); v += __shfl_xor(v,8,64);
        if (l15 == 0)
          atomicAdd(&qacc[(mt>>2)*64 + (mt&3)*16 + quad*4 + r], v);
      }
    }
    __syncthreads();
    if (t < 128) atomicAdd(QP + bh0*64 + t, qacc[t]);
  } else {
    float v0[4] = {0,0,0,0}, v1[4] = {0,0,0,0};
    #pragma unroll
    for (int mt=0;mt<8;mt++){
      #pragma unroll
      for (int r=0;r<4;r++){
        float w = qpl[mt*16 + quad*4 + r];
        #pragma unroll
        for (int nt=0;nt<4;nt++){
          float av = fabsf(acc[mt][nt][r]) * w;
          if (mt < 4) v0[nt] += av; else v1[nt] += av;
        }
      }
    }
    #pragma unroll
    for (int nt=0;nt<4;nt++){
      v0[nt] += __shfl_xor(v0[nt],16,64); v0[nt] += __shfl_xor(v0[nt],32,64);
      v1[nt] += __shfl_xor(v1[nt],16,64); v1[nt] += __shfl_xor(v1[nt],32,64);
      v0[nt] *= inv0[nt]; v1[nt] *= inv1[nt];
    }
    // s = stile*256 + wvi*64 + nt*16 + l15:
    //   w = (nt&1)*16 + l15 ; h = (stile&3)*8 + wvi*2 + (nt>>1) ; d = stile>>2
    float w00 = v0[0]+v0[2], w10 = v0[1]+v0[3];
    float w01 = v1[0]+v1[2], w11 = v1[1]+v1[3];
    float h00 = v0[0]+v0[1], h01 = v0[2]+v0[3];
    float h10 = v1[0]+v1[1], h11 = v1[2]+v1[3];
    #pragma unroll
    for (int mm=1; mm<16; mm<<=1){
      h00 += __shfl_xor(h00,mm,64); h01 += __shfl_xor(h01,mm,64);
      h10 += __shfl_xor(h10,mm,64); h11 += __shfl_xor(h11,mm,64);
    }
    if (lane < 16){
      atomicAdd(&wacc[l15],      w00);
      atomicAdd(&wacc[16+l15],   w10);
      atomicAdd(&wacc[32+l15],   w01);
      atomicAdd(&wacc[48+l15],   w11);
    }
    if (lane == 0){
      int hb = 16 + (stile&3)*8 + wvi*2;
      atomicAdd(SCORE + bh0*80 + hb,     h00);
      atomicAdd(SCORE + bh0*80 + hb + 1, h01);
      atomicAdd(SCORE + (bh0+1)*80 + hb,     h10);
      atomicAdd(SCORE + (bh0+1)*80 + hb + 1, h11);
      atomicAdd(SCORE + bh0*80 + (stile>>2), h00+h01);
      atomicAdd(SCORE + (bh0+1)*80 + (stile>>2), h10+h11);
    }
    __syncthreads();
    if (t < 64) atomicAdd(SCORE + (bh0 + (t>>5))*80 + 48 + (t&31), wacc[t]);
  }
}

// ---------------- K4: topk (inlined, wave 0) + gather-recompute ------------
__global__ __launch_bounds__(256) void k_gather(const float* __restrict__ ctx,
    const float* __restrict__ wkv, const float* __restrict__ ctx_g,
    const float* __restrict__ ctx_b, const float* __restrict__ MEAN,
    const float* __restrict__ INV, const float* __restrict__ SCORE,
    unsigned short* __restrict__ KG, unsigned short* __restrict__ VGT){
  __shared__ float wlds[64*129];
  __shared__ float xln[32*128];
  __shared__ float scb[80];
  __shared__ int sidx[24];
  int bx = blockIdx.x;
  int bh = bx >> 5, jc = (bx >> 1) & 15, type = bx & 1;
  int head = bh & 7, b = bh >> 3;
  int t = threadIdx.x;
  if (t < 80) scb[t] = SCORE[bh*80 + t];
  {
    int oc = t>>2, ks = (t&3)*32;
    const float* wr = wkv + ((size_t)(type*512 + head*64 + oc))*128 + ks;
    #pragma unroll 8
    for (int i=0;i<32;i++) wlds[oc*129 + ks + i] = wr[i];
  }
  __syncthreads();
  if (t < 64){ // wave 0: butterfly top-8 per axis (ties -> lowest idx)
    #pragma unroll 1
    for (int a=0;a<3;a++){
      int n = a ? 32 : 16;
      int off = (a==0) ? 0 : (a==1 ? 16 : 48);
      float v = (t < n) ? scb[off+t] : -3.4e38f;
      #pragma unroll 1
      for (int it=0; it<8; it++){
        float bv = v; int bi = t;
        #pragma unroll
        for (int mm=1; mm<32; mm<<=1){
          float ov = __shfl_xor(bv, mm, 64);
          int oi = __shfl_xor(bi, mm, 64);
          if (ov > bv || (ov == bv && oi < bi)){ bv = ov; bi = oi; }
        }
        if (t == bi) v = -3.4e38f;
        if (t == 0) sidx[a*8+it] = bi;
      }
    }
  }
  __syncthreads();
  {
    int jl = t>>3, seg = (t&7)*16;
    int jj = jc*32 + jl;
    int dsel = sidx[jj>>6], hsel = sidx[8 + ((jj>>3)&7)], wsel = sidx[16 + (jj&7)];
    int sj = dsel*1024 + hsel*32 + wsel;
    float mn = MEAN[b*S_SP + sj];
    float iv = INV[b*S_SP + sj];
    #pragma unroll
    for (int i=0;i<16;i++){
      int cc = seg + i;
      float raw = ctx[((size_t)(b*128 + cc))*S_SP + sj];
      xln[jl*128 + cc] = ctx_g[cc]*(raw - mn)*iv + ctx_b[cc];
    }
  }
  __syncthreads();
  int c = t & 63, jg = t >> 6;
  float accv[8] = {};
  #pragma unroll 4
  for (int k=0;k<128;k++){
    float wv = wlds[c*129 + k];
    #pragma unroll
    for (int m=0;m<8;m++) accv[m] += wv * xln[(jg + 4*m)*128 + k];
  }
  #pragma unroll
  for (int m=0;m<8;m++){
    int jj = jc*32 + jg + 4*m;
    float a = accv[m];
    if (type == 0){
      float sq = a*a;
      #pragma unroll
      for (int mm=32; mm; mm>>=1) sq += __shfl_xor(sq, mm, 64);
      float rn = 1.f/fmaxf(sqrtf(sq), 1e-12f);
      KG[((size_t)bh*NKV + jj)*64 + c] = f2bf(a*rn);
    } else {
      VGT[((size_t)bh*64 + c)*NKV + jj] = f2bf(a);
    }
  }
}

// ---------------- K5: attention, 8-wave async-dbuf, qt-pair P ---------------
// k_attn is wave-count-bound (r7 16 waves/CU = 75us; r11 12 waves/CU = 94us).
// qt-pair P processing (compute+consume P for qt{0,1}, reuse LDS rows for
// qt{2,3}; per-wave LDS ops are in-order -> safe) shrinks pst to [8][32*36]:
// LDS 51200 -> 3 blocks/CU x 8 waves = 24 waves/CU if VGPR <= 85.
// pst stride 36 (18 dwords): conflict-free (r10/r11 measured 0).
__global__ __launch_bounds__(512) void k_attn(const unsigned short* __restrict__ QBF,
    const unsigned short* __restrict__ KG, const unsigned short* __restrict__ VGT,
    unsigned short* __restrict__ AOUT){
  __shared__ __align__(16) unsigned short kst[2][64*64];  // K chunk [j][c] swz
  __shared__ __align__(16) unsigned short vst[2][64*64];  // V chunk [c][j] swz
  __shared__ __align__(16) unsigned short pst[8][32*36];  // per-wave P (qt pair)
  int bx = blockIdx.x;
  int bh = bx >> 5, qb = bx & 31;
  int t = threadIdx.x;
  int wvi = t >> 6, lane = t & 63;
  int quad = lane >> 4, l15 = lane & 15;
  int r3 = lane >> 3, s3 = lane & 7;
  int q0 = qb*512 + wvi*64;
  const unsigned short* kgb = KG + (size_t)bh*NKV*64;
  const unsigned short* vgb = VGT + (size_t)bh*64*NKV;
  // Q fragments as B-operand: n=q=l15, k=c=quad*8+i
  short8 bq[4][2];
  #pragma unroll
  for (int qt=0; qt<4; qt++){
    const unsigned short* qp_ = QBF + ((size_t)bh*S_SP + q0 + qt*16 + l15)*64 + quad*8;
    union { uint4 u; short8 s; } u0, u1;
    u0.u = *(const uint4*)(qp_);
    u1.u = *(const uint4*)(qp_ + 32);
    bq[qt][0] = u0.s; bq[qt][1] = u1.s;
  }
  v4f oacc[4][4]; // [ct][qt]: O^T tile: col=q=l15, row=c=ct*16+quad*4+r
  #pragma unroll
  for (int i=0;i<4;i++)
    #pragma unroll
    for (int j=0;j<4;j++) oacc[i][j] = (v4f){0.f,0.f,0.f,0.f};
  float lsum[4] = {0.f,0.f,0.f,0.f};
  unsigned short* pw = pst[wvi];
  int swz = (s3 ^ r3) << 3;   // pre-swizzled source block (8 shorts)
  // prologue: stage chunk 0 -> buf 0 (each wave: 8 K rows + 8 V rows)
  gll16(kgb + ((size_t)(wvi*8 + r3))*64 + swz,  &kst[0][wvi*512]);
  gll16(vgb + ((size_t)(wvi*8 + r3))*NKV + swz, &vst[0][wvi*512]);
  __syncthreads();
  #pragma unroll 1
  for (int ch=0; ch<8; ch++){
    int cur = ch & 1;
    if (ch < 7){ // async prefetch next chunk into the other buffer
      gll16(kgb + ((size_t)((ch+1)*64 + wvi*8 + r3))*64 + swz, &kst[cur^1][wvi*512]);
      gll16(vgb + ((size_t)(wvi*8 + r3))*NKV + (ch+1)*64 + swz, &vst[cur^1][wvi*512]);
    }
    const unsigned short* kb = kst[cur];
    const unsigned short* vb = vst[cur];
    #pragma unroll
    for (int sub=0; sub<2; sub++){ // 32 j per sub
      #pragma unroll
      for (int pr=0; pr<2; pr++){  // qt pairs {0,1} then {2,3}
        #pragma unroll
        for (int j2=0; j2<2; j2++){
          int jr = (sub*2 + j2)*16 + l15;
          int sk = jr & 7;
          union { uint4 u; short8 s; } a0, a1;
          a0.u = *(const uint4*)(kb + jr*64 + ((quad^sk)*8));
          a1.u = *(const uint4*)(kb + jr*64 + (((quad+4)^sk)*8));
          #pragma unroll
          for (int qh=0; qh<2; qh++){
            int qt = pr*2 + qh;
            v4f z = {0.f,0.f,0.f,0.f};
            __builtin_amdgcn_s_setprio(1);
            z = __builtin_amdgcn_mfma_f32_16x16x32_bf16(a0.s, bq[qt][0], z, 0, 0, 0);
            z = __builtin_amdgcn_mfma_f32_16x16x32_bf16(a1.s, bq[qt][1], z, 0, 0, 0);
            __builtin_amdgcn_s_setprio(0);
            v4f p;
            #pragma unroll
            for (int r=0;r<4;r++) p[r] = __expf(z[r] - 1.0f);
            lsum[qt] += p[0]+p[1]+p[2]+p[3];
            uint2 wv;
            wv.x = pk2(p[0], p[1]);
            wv.y = pk2(p[2], p[3]);
            *(uint2*)&pw[(qh*16 + l15)*36 + j2*16 + quad*4] = wv;
          }
        }
        // PV for this qt pair: O^T += V^T(64c x 32j) . P^T(32j x 32q-pair)
        short8 bp0, bp1;
        {
          union { uint4 u; short8 s; } ub;
          ub.u = *(const uint4*)&pw[l15*36 + quad*8];
          bp0 = ub.s;
          ub.u = *(const uint4*)&pw[(16 + l15)*36 + quad*8];
          bp1 = ub.s;
        }
        #pragma unroll
        for (int ct=0; ct<4; ct++){
          int cr = ct*16 + l15;
          union { uint4 u; short8 s; } av;
          av.u = *(const uint4*)(vb + cr*64 + (((sub*4+quad)^(cr&7))*8));
          __builtin_amdgcn_s_setprio(1);
          oacc[ct][pr*2]   = __builtin_amdgcn_mfma_f32_16x16x32_bf16(av.s, bp0, oacc[ct][pr*2], 0, 0, 0);
          oacc[ct][pr*2+1] = __builtin_amdgcn_mfma_f32_16x16x32_bf16(av.s, bp1, oacc[ct][pr*2+1], 0, 0, 0);
          __builtin_amdgcn_s_setprio(0);
        }
      }
    }
    __syncthreads();  // drains vmcnt: prefetched chunk landed; LDS reads done
  }
  float rl[4];
  #pragma unroll
  for (int qt=0; qt<4; qt++){
    float l = lsum[qt];
    l += __shfl_xor(l, 16, 64);
    l += __shfl_xor(l, 32, 64);
    rl[qt] = 1.f/l;
  }
  #pragma unroll
  for (int qt=0; qt<4; qt++){
    #pragma unroll
    for (int ct=0; ct<4; ct++){
      v4f o = oacc[ct][qt];
      uint2 wv;
      wv.x = pk2(o[0]*rl[qt], o[1]*rl[qt]);
      wv.y = pk2(o[2]*rl[qt], o[3]*rl[qt]);
      *(uint2*)(AOUT + ((size_t)bh*S_SP + q0 + qt*16 + l15)*64 + ct*16 + quad*4) = wv;
    }
  }
}

// ---------------- K6: out-projection via MFMA bf16 + LN + residual ---------
__global__ __launch_bounds__(256) void k_out(const unsigned short* __restrict__ AOUT,
    const float* __restrict__ wout, const float* __restrict__ out_g,
    const float* __restrict__ out_b, const float* __restrict__ gamma,
    const float* __restrict__ qsrc, float* __restrict__ OUT){
  __shared__ __align__(16) unsigned short wl[128*40];
  __shared__ float lnp[4][2][64];
  __shared__ float mbuf[64], sbuf[64], ogl[128], obl[128];
  int bx = blockIdx.x; int b = bx>>8; int stile = bx&255; int s0 = stile*64;
  int t = threadIdx.x; int w = t>>6; int lane = t&63;
  int q = lane>>4; int l15 = lane&15;
  if (t < 128){ ogl[t] = out_g[t]; obl[t] = out_b[t]; }
  v4f acc[2][4];
  #pragma unroll
  for (int i=0;i<2;i++)
    #pragma unroll
    for (int j=0;j<4;j++) acc[i][j] = (v4f){0.f,0.f,0.f,0.f};
  for (int kt=0; kt<16; kt++){
    __syncthreads();
    {
      int c = t>>1, kb = (t&1)*16;
      const float* wr = wout + (size_t)c*512 + kt*32 + kb;
      v4f a0 = *(const v4f*)wr, a1 = *(const v4f*)(wr+4);
      v4f a2 = *(const v4f*)(wr+8), a3 = *(const v4f*)(wr+12);
      uint4 u0, u1;
      u0.x = pk2(a0[0], a0[1]); u0.y = pk2(a0[2], a0[3]);
      u0.z = pk2(a1[0], a1[1]); u0.w = pk2(a1[2], a1[3]);
      u1.x = pk2(a2[0], a2[1]); u1.y = pk2(a2[2], a2[3]);
      u1.z = pk2(a3[0], a3[1]); u1.w = pk2(a3[2], a3[3]);
      *(uint4*)&wl[c*40+kb]   = u0;
      *(uint4*)&wl[c*40+kb+8] = u1;
    }
    __syncthreads();
    short8 af[2];
    #pragma unroll
    for (int mt=0;mt<2;mt++){
      union { uint4 u; short8 s; } ua;
      ua.u = *(const uint4*)&wl[(w*32+mt*16+l15)*40 + q*8];
      af[mt] = ua.s;
    }
    int head = kt>>1; int cc0 = (kt&1)*32 + q*8;
    const unsigned short* bp = AOUT + ((size_t)((b*8+head)*S_SP + s0 + l15))*64 + cc0;
    #pragma unroll
    for (int nt=0;nt<4;nt++){
      union { uint4 u; short8 s; } ub;
      ub.u = *(const uint4*)(bp + (size_t)nt*16*64);
      #pragma unroll
      for (int mt=0;mt<2;mt++)
        acc[mt][nt] = __builtin_amdgcn_mfma_f32_16x16x32_bf16(af[mt], ub.s, acc[mt][nt], 0, 0, 0);
    }
  }
  #pragma unroll
  for (int nt=0;nt<4;nt++){
    float p1 = 0.f, p2 = 0.f;
    #pragma unroll
    for (int mt=0;mt<2;mt++)
      #pragma unroll
      for (int r=0;r<4;r++){ float v = acc[mt][nt][r]; p1 += v; p2 += v*v; }
    p1 += __shfl_xor(p1,16,64); p1 += __shfl_xor(p1,32,64);
    p2 += __shfl_xor(p2,16,64); p2 += __shfl_xor(p2,32,64);
    if (q == 0){ lnp[w][0][nt*16+l15] = p1; lnp[w][1][nt*16+l15] = p2; }
  }
  __syncthreads();
  if (t < 64){
    float m = (lnp[0][0][t]+lnp[1][0][t]+lnp[2][0][t]+lnp[3][0][t]) * 0.0078125f;
    float qq = (lnp[0][1][t]+lnp[1][1][t]+lnp[2][1][t]+lnp[3][1][t]) * 0.0078125f;
    float var = fmaxf(qq - m*m, 0.f);
    mbuf[t] = m;
    sbuf[t] = 1.f/(sqrtf(var) + 1e-6f);
  }
  __syncthreads();
  float gs = gamma[0];
  #pragma unroll
  for (int nt=0;nt<4;nt++){
    int sl = nt*16 + l15;
    float mm = mbuf[sl], ssc = sbuf[sl];
    #pragma unroll
    for (int mt=0;mt<2;mt++){
      #pragma unroll
      for (int r=0;r<4;r++){
        int c = w*32 + mt*16 + q*4 + r;
        size_t adr = ((size_t)(b*128+c))*S_SP + s0 + sl;
        float yn = (acc[mt][nt][r]-mm)*ssc;
        OUT[adr] = gs*(ogl[c]*yn + obl[c]) + qsrc[adr];
      }
    }
  }
}

extern "C" void kernel_launch(void* const* d_in, const int* in_sizes, int n_in,
                              void* d_out, int out_size, void* d_ws, size_t ws_size,
                              hipStream_t stream){
  const float* qsrc  = (const float*)d_in[0];
  const float* ctx   = (const float*)d_in[1];
  const float* wq    = (const float*)d_in[2];
  const float* wkv   = (const float*)d_in[3];
  const float* wout  = (const float*)d_in[4];
  const float* ctx_g = (const float*)d_in[5];
  const float* ctx_b = (const float*)d_in[6];
  const float* qs_g  = (const float*)d_in[7];
  const float* qs_b  = (const float*)d_in[8];
  const float* out_g = (const float*)d_in[9];
  const float* out_b = (const float*)d_in[10];
  const float* gamma = (const float*)d_in[11];
  float* OUT = (float*)d_out;
  char* ws = (char*)d_ws;
  float* QP    = (float*)(ws);
  float* SCORE = (float*)(ws + 4096);
  float* MEAN  = (float*)(ws + 16384);
  float* INV   = (float*)(ws + 278528);
  unsigned short* QBF  = (unsigned short*)(ws + 544768);
  unsigned short* KG   = (unsigned short*)(ws + 34099200);
  unsigned short* VGT  = (unsigned short*)(ws + 35147776);
  unsigned short* AOUT = (unsigned short*)(ws + 36196352);
  // W hi/lo alias the KG region (dead until k_gather runs)
  unsigned short* WQh = (unsigned short*)(ws + 34099200);
  unsigned short* WQl = (unsigned short*)(ws + 34230272);
  unsigned short* WKh = (unsigned short*)(ws + 34361344);
  unsigned short* WKl = (unsigned short*)(ws + 34492416);
  // XT hi/lo alias the AOUT region (dead until k_attn runs); ends at 69750784
  unsigned short* XTQh = (unsigned short*)(ws + 36196352);
  unsigned short* XTQl = (unsigned short*)(ws + 44584960);
  unsigned short* XTCh = (unsigned short*)(ws + 52973568);
  unsigned short* XTCl = (unsigned short*)(ws + 61362176);

  hipMemsetAsync(ws, 0, 9216, stream); // QP + SCORE
  k_stats<<<1088, 256, 0, stream>>>(ctx, qsrc, ctx_g, ctx_b, qs_g, qs_b, wq, wkv,
                                    MEAN, INV, XTCh, XTCl, XTQh, XTQl,
                                    WQh, WQl, WKh, WKl);
  k_proj<0><<<512, 256, 0, stream>>>(XTQh, XTQl, WQh, WQl, QBF, QP, SCORE);
  k_proj<1><<<512, 256, 0, stream>>>(XTCh, XTCl, WKh, WKl, QBF, QP, SCORE);
  k_gather<<<512, 256, 0, stream>>>(ctx, wkv, ctx_g, ctx_b, MEAN, INV, SCORE, KG, VGT);
  k_attn<<<512, 512, 0, stream>>>(QBF, KG, VGT, AOUT);
  k_out<<<512, 256, 0, stream>>>(AOUT, wout, out_g, out_b, gamma, qsrc, OUT);
}

// Round 17
// 298.911 us; speedup vs baseline: 1.2092x; 1.1214x over previous
//
#include <hip/hip_runtime.h>
#include <hip/hip_bf16.h>

#define S_SP 16384
#define NKV 512

typedef short short8 __attribute__((ext_vector_type(8)));
typedef float v4f   __attribute__((ext_vector_type(4)));

__device__ __forceinline__ unsigned short f2bf(float x){
  union { float f; unsigned u; } v; v.f = x;
  unsigned r = v.u + 0x7FFFu + ((v.u >> 16) & 1u);
  return (unsigned short)(r >> 16);
}
__device__ __forceinline__ float bf2f(unsigned short h){
  union { unsigned u; float f; } v; v.u = ((unsigned)h) << 16; return v.f;
}

#if defined(__has_builtin)
#if __has_builtin(__builtin_amdgcn_cvt_pk_bf16_f32)
#define HAVE_PKBF 1
#endif
#endif

__device__ __forceinline__ unsigned pk2(float a, float b){
#ifdef HAVE_PKBF
  typedef __bf16 bf16x2 __attribute__((ext_vector_type(2)));
  union { bf16x2 v; unsigned u; } r;
  r.v = __builtin_amdgcn_cvt_pk_bf16_f32(a, b);
  return r.u;
#else
  return (unsigned)f2bf(a) | ((unsigned)f2bf(b) << 16);
#endif
}

__device__ __forceinline__ short8 u2s8(uint4 u){
  union { uint4 u; short8 s; } x; x.u = u; return x.s;
}

// ---------------- K1: channel-LN stats + pre-LN'd transposed bf16 hi/lo copy
// Blocks [0,1024): stats + XT emit. Blocks [1024,1088): W hi/lo split.
__global__ __launch_bounds__(256) void k_stats(const float* __restrict__ ctx,
                                               const float* __restrict__ qs,
                                               const float* __restrict__ ctx_g,
                                               const float* __restrict__ ctx_b,
                                               const float* __restrict__ qs_g,
                                               const float* __restrict__ qs_b,
                                               const float* __restrict__ wq,
                                               const float* __restrict__ wkv,
                                               float* __restrict__ MEAN,
                                               float* __restrict__ INV,
                                               unsigned short* __restrict__ XTC_hi,
                                               unsigned short* __restrict__ XTC_lo,
                                               unsigned short* __restrict__ XTQ_hi,
                                               unsigned short* __restrict__ XTQ_lo,
                                               unsigned short* __restrict__ WQh,
                                               unsigned short* __restrict__ WQl,
                                               unsigned short* __restrict__ WKh,
                                               unsigned short* __restrict__ WKl){
  __shared__ float r1[4][64];
  __shared__ float r2[4][64];
  __shared__ float mb[64], ib[64];
  __shared__ __align__(16) unsigned short TH[64*136];
  __shared__ __align__(16) unsigned short TL[64*136];
  int bx = blockIdx.x;
  int t = threadIdx.x;
  if (bx >= 1024){ // W hi/lo split: wq (512x128) then wkv K-half (512x128)
    int wb = bx - 1024;
    int isK = wb >> 5;
    size_t i8 = ((size_t)(wb & 31)*256 + t)*8;
    const float* srcw = isK ? wkv : wq;
    unsigned short* dh = isK ? WKh : WQh;
    unsigned short* dl = isK ? WKl : WQl;
    v4f a  = *(const v4f*)(srcw + i8);
    v4f b2 = *(const v4f*)(srcw + i8 + 4);
    unsigned short h[8], l[8];
    #pragma unroll
    for (int i=0;i<4;i++){
      h[i]   = f2bf(a[i]);  l[i]   = f2bf(a[i]  - bf2f(h[i]));
      h[i+4] = f2bf(b2[i]); l[i+4] = f2bf(b2[i] - bf2f(h[i+4]));
    }
    uint4 uh, ul;
    uh.x = (unsigned)h[0] | ((unsigned)h[1]<<16);
    uh.y = (unsigned)h[2] | ((unsigned)h[3]<<16);
    uh.z = (unsigned)h[4] | ((unsigned)h[5]<<16);
    uh.w = (unsigned)h[6] | ((unsigned)h[7]<<16);
    ul.x = (unsigned)l[0] | ((unsigned)l[1]<<16);
    ul.y = (unsigned)l[2] | ((unsigned)l[3]<<16);
    ul.z = (unsigned)l[4] | ((unsigned)l[5]<<16);
    ul.w = (unsigned)l[6] | ((unsigned)l[7]<<16);
    *(uint4*)(dh + i8) = uh;
    *(uint4*)(dl + i8) = ul;
    return;
  }
  int tt = bx >> 9; int b = (bx >> 8) & 1; int sc = bx & 255;
  int sv = t & 63, cg = t >> 6;
  int s = sc*64 + sv;
  const float* src = (tt ? qs : ctx) + ((size_t)b*128 + cg*32)*S_SP + s;
  const float* G  = tt ? qs_g : ctx_g;
  const float* Bv = tt ? qs_b : ctx_b;
  float xv[32];
  float sum = 0.f, ss = 0.f;
  #pragma unroll
  for (int c = 0; c < 32; c++){
    float v = src[(size_t)c*S_SP];
    xv[c] = v;
    sum += v; ss += v*v;
  }
  r1[cg][sv] = sum; r2[cg][sv] = ss;
  __syncthreads();
  if (t < 64){
    float sm = r1[0][t]+r1[1][t]+r1[2][t]+r1[3][t];
    float sq = r2[0][t]+r2[1][t]+r2[2][t]+r2[3][t];
    float mean = sm * 0.0078125f;
    float var  = fmaxf(sq * 0.0078125f - mean*mean, 0.f);
    float inv  = 1.f/(sqrtf(var) + 1e-6f);
    int o = tt*2*S_SP + b*S_SP + sc*64 + t;
    MEAN[o] = mean; INV[o] = inv;   // consumed by k_gather (tt=0)
    mb[t] = mean; ib[t] = inv;
  }
  __syncthreads();
  float m = mb[sv], iv = ib[sv];
  #pragma unroll
  for (int i = 0; i < 32; i += 2){
    int c = cg*32 + i;
    float y0 = G[c]  *(xv[i]  -m)*iv + Bv[c];
    float y1 = G[c+1]*(xv[i+1]-m)*iv + Bv[c+1];
    unsigned short h0 = f2bf(y0), h1 = f2bf(y1);
    unsigned short l0 = f2bf(y0 - bf2f(h0)), l1 = f2bf(y1 - bf2f(h1));
    *(unsigned*)&TH[sv*136 + c] = (unsigned)h0 | ((unsigned)h1 << 16);
    *(unsigned*)&TL[sv*136 + c] = (unsigned)l0 | ((unsigned)l1 << 16);
  }
  __syncthreads();
  int row = t >> 2, seg = (t & 3) * 32;
  unsigned short* XH = tt ? XTQ_hi : XTC_hi;
  unsigned short* XL = tt ? XTQ_lo : XTC_lo;
  size_t go = ((size_t)b*S_SP + sc*64 + row)*128 + seg;
  #pragma unroll
  for (int k2 = 0; k2 < 4; k2++){
    *(uint4*)(XH + go + k2*8) = *(const uint4*)&TH[row*136 + seg + k2*8];
    *(uint4*)(XL + go + k2*8) = *(const uint4*)&TL[row*136 + seg + k2*8];
  }
}

// ---------------- K2: projection as split-bf16 3-pass MFMA ------------------
// D = Ah*Bh + Ah*Bl + Al*Bh  ~  fp32-accurate (missing Al*Bl ~2^-18).
template<int ISK>
__global__ __launch_bounds__(256, 2) void k_proj(
    const unsigned short* __restrict__ XH, const unsigned short* __restrict__ XL,
    const unsigned short* __restrict__ WH, const unsigned short* __restrict__ WL,
    unsigned short* __restrict__ QBF, float* __restrict__ QP,
    float* __restrict__ SCORE){
  __shared__ float qpl[128];
  __shared__ float qacc[128];  // !ISK: block-reduced q_probe
  __shared__ float wacc[64];   // ISK: block-reduced w-axis scores [head*32+w]
  int bx = blockIdx.x;
  int og = bx >> 7, b = (bx >> 6) & 1, stile = bx & 63;
  int t = threadIdx.x, wvi = t >> 6, lane = t & 63;
  int quad = lane >> 4, l15 = lane & 15;
  int sw0 = stile*256 + wvi*64;
  int bh0 = b*8 + og*2;
  if (ISK){
    if (t < 128) qpl[t] = QP[bh0*64 + t];
    if (t < 64) wacc[t] = 0.f;
    __syncthreads();
  } else {
    if (t < 128) qacc[t] = 0.f;  // ordered by the epilogue barrier
  }
  v4f acc[8][4];
  #pragma unroll
  for (int i=0;i<8;i++)
    #pragma unroll
    for (int j=0;j<4;j++) acc[i][j] = (v4f){0.f,0.f,0.f,0.f};
  size_t wrow = ((size_t)(og*128 + l15))*128 + quad*8;
  size_t xrow = ((size_t)b*S_SP + sw0 + l15)*128 + quad*8;
  #pragma unroll 1
  for (int ks=0; ks<4; ks++){
    int ko = ks*32;
    uint4 bhv[4], blv[4], av[8];
    #pragma unroll
    for (int nt=0;nt<4;nt++){
      bhv[nt] = *(const uint4*)(XH + xrow + nt*2048 + ko);
      blv[nt] = *(const uint4*)(XL + xrow + nt*2048 + ko);
    }
    #pragma unroll
    for (int mt=0;mt<8;mt++) av[mt] = *(const uint4*)(WH + wrow + mt*2048 + ko);
    #pragma unroll
    for (int mt=0;mt<8;mt++){
      short8 am = u2s8(av[mt]);
      #pragma unroll
      for (int nt=0;nt<4;nt++)
        acc[mt][nt] = __builtin_amdgcn_mfma_f32_16x16x32_bf16(am, u2s8(bhv[nt]), acc[mt][nt], 0, 0, 0);
      #pragma unroll
      for (int nt=0;nt<4;nt++)
        acc[mt][nt] = __builtin_amdgcn_mfma_f32_16x16x32_bf16(am, u2s8(blv[nt]), acc[mt][nt], 0, 0, 0);
    }
    #pragma unroll
    for (int mt=0;mt<8;mt++){
      short8 am = u2s8(*(const uint4*)(WL + wrow + mt*2048 + ko));
      #pragma unroll
      for (int nt=0;nt<4;nt++)
        acc[mt][nt] = __builtin_amdgcn_mfma_f32_16x16x32_bf16(am, u2s8(bhv[nt]), acc[mt][nt], 0, 0, 0);
    }
  }
  // per-head l2norm inverses (per spatial col): in-lane + quad shfl reduce
  float inv0[4], inv1[4];
  #pragma unroll
  for (int nt=0;nt<4;nt++){
    float p0 = 0.f, p1 = 0.f;
    #pragma unroll
    for (int mt=0;mt<4;mt++)
      #pragma unroll
      for (int r=0;r<4;r++){
        p0 += acc[mt][nt][r]*acc[mt][nt][r];
        p1 += acc[mt+4][nt][r]*acc[mt+4][nt][r];
      }
    p0 += __shfl_xor(p0,16,64); p0 += __shfl_xor(p0,32,64);
    p1 += __shfl_xor(p1,16,64); p1 += __shfl_xor(p1,32,64);
    inv0[nt] = 1.f/fmaxf(sqrtf(p0),1e-12f);
    inv1[nt] = 1.f/fmaxf(sqrtf(p1),1e-12f);
  }
  if (!ISK){
    #pragma unroll
    for (int mt=0;mt<8;mt++)
      #pragma unroll
      for (int nt=0;nt<4;nt++){
        float iv = (mt<4) ? inv0[nt] : inv1[nt];
        #pragma unroll
        for (int r=0;r<4;r++) acc[mt][nt][r] *= iv;
      }
    // QBF: [bh][s][64c] bf16 (layout k_attn expects)
    #pragma unroll
    for (int mt=0;mt<8;mt++){
      int bh = bh0 + (mt>>2);
      #pragma unroll
      for (int nt=0;nt<4;nt++){
        int s = sw0 + nt*16 + l15;
        uint2 wv;
        wv.x = pk2(acc[mt][nt][0], acc[mt][nt][1]);
        wv.y = pk2(acc[mt][nt][2], acc[mt][nt][3]);
        *(uint2*)(QBF + ((size_t)bh*S_SP + s)*64 + (mt&3)*16 + quad*4) = wv;
      }
    }
    __syncthreads();  // orders qacc zeroing before LDS atomics
    #pragma unroll
    for (int mt=0;mt<8;mt++){
      #pragma unroll
      for (int r=0;r<4;r++){
        float v = acc[mt][0][r]+acc[mt][1][r]+acc[mt][2][r]+acc[mt][3][r];
        v += __shfl_xor(v,1,64); v += __shfl_xor(v,2,64);
        v += __shfl_xor(v,4,64); v += __shfl_xor(v,8,64);
        if (l15 == 0)
          atomicAdd(&qacc[(mt>>2)*64 + (mt&3)*16 + quad*4 + r], v);
      }
    }
    __syncthreads();
    if (t < 128) atomicAdd(QP + bh0*64 + t, qacc[t]);
  } else {
    float v0[4] = {0,0,0,0}, v1[4] = {0,0,0,0};
    #pragma unroll
    for (int mt=0;mt<8;mt++){
      #pragma unroll
      for (int r=0;r<4;r++){
        float w = qpl[mt*16 + quad*4 + r];
        #pragma unroll
        for (int nt=0;nt<4;nt++){
          float av = fabsf(acc[mt][nt][r]) * w;
          if (mt < 4) v0[nt] += av; else v1[nt] += av;
        }
      }
    }
    #pragma unroll
    for (int nt=0;nt<4;nt++){
      v0[nt] += __shfl_xor(v0[nt],16,64); v0[nt] += __shfl_xor(v0[nt],32,64);
      v1[nt] += __shfl_xor(v1[nt],16,64); v1[nt] += __shfl_xor(v1[nt],32,64);
      v0[nt] *= inv0[nt]; v1[nt] *= inv1[nt];
    }
    // s = stile*256 + wvi*64 + nt*16 + l15:
    //   w = (nt&1)*16 + l15 ; h = (stile&3)*8 + wvi*2 + (nt>>1) ; d = stile>>2
    float w00 = v0[0]+v0[2], w10 = v0[1]+v0[3];
    float w01 = v1[0]+v1[2], w11 = v1[1]+v1[3];
    float h00 = v0[0]+v0[1], h01 = v0[2]+v0[3];
    float h10 = v1[0]+v1[1], h11 = v1[2]+v1[3];
    #pragma unroll
    for (int mm=1; mm<16; mm<<=1){
      h00 += __shfl_xor(h00,mm,64); h01 += __shfl_xor(h01,mm,64);
      h10 += __shfl_xor(h10,mm,64); h11 += __shfl_xor(h11,mm,64);
    }
    if (lane < 16){
      atomicAdd(&wacc[l15],      w00);
      atomicAdd(&wacc[16+l15],   w10);
      atomicAdd(&wacc[32+l15],   w01);
      atomicAdd(&wacc[48+l15],   w11);
    }
    if (lane == 0){
      int hb = 16 + (stile&3)*8 + wvi*2;
      atomicAdd(SCORE + bh0*80 + hb,     h00);
      atomicAdd(SCORE + bh0*80 + hb + 1, h01);
      atomicAdd(SCORE + (bh0+1)*80 + hb,     h10);
      atomicAdd(SCORE + (bh0+1)*80 + hb + 1, h11);
      atomicAdd(SCORE + bh0*80 + (stile>>2), h00+h01);
      atomicAdd(SCORE + (bh0+1)*80 + (stile>>2), h10+h11);
    }
    __syncthreads();
    if (t < 64) atomicAdd(SCORE + (bh0 + (t>>5))*80 + 48 + (t&31), wacc[t]);
  }
}

// ---------------- K4: topk (inlined, wave 0) + gather-recompute ------------
__global__ __launch_bounds__(256) void k_gather(const float* __restrict__ ctx,
    const float* __restrict__ wkv, const float* __restrict__ ctx_g,
    const float* __restrict__ ctx_b, const float* __restrict__ MEAN,
    const float* __restrict__ INV, const float* __restrict__ SCORE,
    unsigned short* __restrict__ KG, unsigned short* __restrict__ VGT){
  __shared__ float wlds[64*129];
  __shared__ float xln[32*128];
  __shared__ float scb[80];
  __shared__ int sidx[24];
  int bx = blockIdx.x;
  int bh = bx >> 5, jc = (bx >> 1) & 15, type = bx & 1;
  int head = bh & 7, b = bh >> 3;
  int t = threadIdx.x;
  if (t < 80) scb[t] = SCORE[bh*80 + t];
  {
    int oc = t>>2, ks = (t&3)*32;
    const float* wr = wkv + ((size_t)(type*512 + head*64 + oc))*128 + ks;
    #pragma unroll 8
    for (int i=0;i<32;i++) wlds[oc*129 + ks + i] = wr[i];
  }
  __syncthreads();
  if (t < 64){ // wave 0: butterfly top-8 per axis (ties -> lowest idx)
    #pragma unroll 1
    for (int a=0;a<3;a++){
      int n = a ? 32 : 16;
      int off = (a==0) ? 0 : (a==1 ? 16 : 48);
      float v = (t < n) ? scb[off+t] : -3.4e38f;
      #pragma unroll 1
      for (int it=0; it<8; it++){
        float bv = v; int bi = t;
        #pragma unroll
        for (int mm=1; mm<32; mm<<=1){
          float ov = __shfl_xor(bv, mm, 64);
          int oi = __shfl_xor(bi, mm, 64);
          if (ov > bv || (ov == bv && oi < bi)){ bv = ov; bi = oi; }
        }
        if (t == bi) v = -3.4e38f;
        if (t == 0) sidx[a*8+it] = bi;
      }
    }
  }
  __syncthreads();
  {
    int jl = t>>3, seg = (t&7)*16;
    int jj = jc*32 + jl;
    int dsel = sidx[jj>>6], hsel = sidx[8 + ((jj>>3)&7)], wsel = sidx[16 + (jj&7)];
    int sj = dsel*1024 + hsel*32 + wsel;
    float mn = MEAN[b*S_SP + sj];
    float iv = INV[b*S_SP + sj];
    #pragma unroll
    for (int i=0;i<16;i++){
      int cc = seg + i;
      float raw = ctx[((size_t)(b*128 + cc))*S_SP + sj];
      xln[jl*128 + cc] = ctx_g[cc]*(raw - mn)*iv + ctx_b[cc];
    }
  }
  __syncthreads();
  int c = t & 63, jg = t >> 6;
  float accv[8] = {};
  #pragma unroll 4
  for (int k=0;k<128;k++){
    float wv = wlds[c*129 + k];
    #pragma unroll
    for (int m=0;m<8;m++) accv[m] += wv * xln[(jg + 4*m)*128 + k];
  }
  #pragma unroll
  for (int m=0;m<8;m++){
    int jj = jc*32 + jg + 4*m;
    float a = accv[m];
    if (type == 0){
      float sq = a*a;
      #pragma unroll
      for (int mm=32; mm; mm>>=1) sq += __shfl_xor(sq, mm, 64);
      float rn = 1.f/fmaxf(sqrtf(sq), 1e-12f);
      KG[((size_t)bh*NKV + jj)*64 + c] = f2bf(a*rn);
    } else {
      VGT[((size_t)bh*64 + c)*NKV + jj] = f2bf(a);
    }
  }
}

// ---------------- K5: attention, S^T=K.Q^T / O^T=V^T.P^T, fixed-max softmax -
// LDS: XOR-swizzled 16B blocks (blk ^= row&7 / row&3) on kst/vst; per-wave
// pst. 48 KiB total -> 3 blocks/CU. |sim|<=1 => softmax == exp(s-1)/sum.
__global__ __launch_bounds__(256) void k_attn(const unsigned short* __restrict__ QBF,
    const unsigned short* __restrict__ KG, const unsigned short* __restrict__ VGT,
    unsigned short* __restrict__ AOUT){
  __shared__ __align__(16) unsigned short kst[128*64];   // K chunk [j][c], swz
  __shared__ __align__(16) unsigned short vst[64*128];   // V chunk [c][j], swz
  __shared__ __align__(16) unsigned short pst[4][64*32]; // per-wave P [q][j], swz
  int bx = blockIdx.x;
  int bh = bx >> 6, qb = bx & 63;
  int t = threadIdx.x;
  int wvi = t >> 6, lane = t & 63;
  int quad = lane >> 4, l15 = lane & 15;
  int q0 = qb*256 + wvi*64;
  const unsigned short* kgb = KG + (size_t)bh*NKV*64;
  const unsigned short* vgb = VGT + (size_t)bh*64*NKV;
  short8 bq[4][2];
  #pragma unroll
  for (int qt=0; qt<4; qt++){
    const unsigned short* qp_ = QBF + ((size_t)bh*S_SP + q0 + qt*16 + l15)*64 + quad*8;
    union { uint4 u; short8 s; } u0, u1;
    u0.u = *(const uint4*)(qp_);
    u1.u = *(const uint4*)(qp_ + 32);
    bq[qt][0] = u0.s; bq[qt][1] = u1.s;
  }
  v4f oacc[4][4]; // [ct][qt]: O^T tile: col=q=l15, row=c=ct*16+quad*4+r
  #pragma unroll
  for (int i=0;i<4;i++)
    #pragma unroll
    for (int j=0;j<4;j++) oacc[i][j] = (v4f){0.f,0.f,0.f,0.f};
  float lsum[4] = {0.f,0.f,0.f,0.f};
  unsigned short* pw = pst[wvi];
  for (int ch=0; ch<4; ch++){
    __syncthreads();
    { // stage K chunk [128 j][64 c]; block swz: blk' = blk ^ (j&7)
      int jl = t>>1, bb = (t&1)*4;
      const unsigned short* sp = kgb + (size_t)(ch*128 + jl)*64 + (t&1)*32;
      unsigned short* dp = kst + jl*64;
      int sw = jl & 7;
      #pragma unroll
      for (int i=0;i<4;i++) *(uint4*)(dp + (((bb+i)^sw)*8)) = *(const uint4*)(sp + i*8);
    }
    { // stage V chunk [64 c][128 j]; block swz: blk' = blk ^ (c&7)
      int cc = t>>2, bb = (t&3)*4;
      const unsigned short* sp = vgb + (size_t)cc*NKV + ch*128 + (t&3)*32;
      unsigned short* dp = vst + cc*128;
      int sw = cc & 7;
      #pragma unroll
      for (int i=0;i<4;i++) *(uint4*)(dp + (((bb+i)^sw)*8)) = *(const uint4*)(sp + i*8);
    }
    __syncthreads();
    #pragma unroll
    for (int sub=0; sub<4; sub++){ // 32 j per sub
      v4f s[2][4];
      #pragma unroll
      for (int j2=0; j2<2; j2++){
        int jr = (sub*2 + j2)*16 + l15;
        const unsigned short* kr = kst + jr*64;
        int sk = jr & 7;
        union { uint4 u; short8 s; } a0, a1;
        a0.u = *(const uint4*)(kr + ((quad^sk)*8));
        a1.u = *(const uint4*)(kr + (((quad+4)^sk)*8));
        __builtin_amdgcn_s_setprio(1);
        #pragma unroll
        for (int qt=0; qt<4; qt++){
          v4f z = {0.f,0.f,0.f,0.f};
          z = __builtin_amdgcn_mfma_f32_16x16x32_bf16(a0.s, bq[qt][0], z, 0, 0, 0);
          z = __builtin_amdgcn_mfma_f32_16x16x32_bf16(a1.s, bq[qt][1], z, 0, 0, 0);
          s[j2][qt] = z;
        }
        __builtin_amdgcn_s_setprio(0);
      }
      #pragma unroll
      for (int j2=0; j2<2; j2++){
        #pragma unroll
        for (int qt=0; qt<4; qt++){
          v4f p;
          #pragma unroll
          for (int r=0;r<4;r++) p[r] = __expf(s[j2][qt][r] - 1.0f);
          lsum[qt] += p[0]+p[1]+p[2]+p[3];
          uint2 wv;
          wv.x = pk2(p[0], p[1]);
          wv.y = pk2(p[2], p[3]);
          int qr = qt*16 + l15;
          *(uint2*)&pw[qr*32 + (((j2*2+(quad>>1))^(qr&3))*8) + (quad&1)*4] = wv;
        }
      }
      short8 bp[4];
      #pragma unroll
      for (int qt=0; qt<4; qt++){
        int qr = qt*16 + l15;
        union { uint4 u; short8 s; } ub;
        ub.u = *(const uint4*)&pw[qr*32 + ((quad^(qr&3))*8)];
        bp[qt] = ub.s;
      }
      #pragma unroll
      for (int ct=0; ct<4; ct++){
        int cr = ct*16 + l15;
        union { uint4 u; short8 s; } av;
        av.u = *(const uint4*)&vst[cr*128 + (((sub*4+quad)^(cr&7))*8)];
        __builtin_amdgcn_s_setprio(1);
        #pragma unroll
        for (int qt=0; qt<4; qt++)
          oacc[ct][qt] = __builtin_amdgcn_mfma_f32_16x16x32_bf16(av.s, bp[qt], oacc[ct][qt], 0, 0, 0);
        __builtin_amdgcn_s_setprio(0);
      }
    }
  }
  float rl[4];
  #pragma unroll
  for (int qt=0; qt<4; qt++){
    float l = lsum[qt];
    l += __shfl_xor(l, 16, 64);
    l += __shfl_xor(l, 32, 64);
    rl[qt] = 1.f/l;
  }
  #pragma unroll
  for (int qt=0; qt<4; qt++){
    #pragma unroll
    for (int ct=0; ct<4; ct++){
      v4f o = oacc[ct][qt];
      uint2 wv;
      wv.x = pk2(o[0]*rl[qt], o[1]*rl[qt]);
      wv.y = pk2(o[2]*rl[qt], o[3]*rl[qt]);
      *(uint2*)(AOUT + ((size_t)bh*S_SP + q0 + qt*16 + l15)*64 + ct*16 + quad*4) = wv;
    }
  }
}

// ---------------- K6: out-projection via MFMA bf16 + LN + residual ---------
__global__ __launch_bounds__(256) void k_out(const unsigned short* __restrict__ AOUT,
    const float* __restrict__ wout, const float* __restrict__ out_g,
    const float* __restrict__ out_b, const float* __restrict__ gamma,
    const float* __restrict__ qsrc, float* __restrict__ OUT){
  __shared__ __align__(16) unsigned short wl[128*40];
  __shared__ float lnp[4][2][64];
  __shared__ float mbuf[64], sbuf[64], ogl[128], obl[128];
  int bx = blockIdx.x; int b = bx>>8; int stile = bx&255; int s0 = stile*64;
  int t = threadIdx.x; int w = t>>6; int lane = t&63;
  int q = lane>>4; int l15 = lane&15;
  if (t < 128){ ogl[t] = out_g[t]; obl[t] = out_b[t]; }
  v4f acc[2][4];
  #pragma unroll
  for (int i=0;i<2;i++)
    #pragma unroll
    for (int j=0;j<4;j++) acc[i][j] = (v4f){0.f,0.f,0.f,0.f};
  for (int kt=0; kt<16; kt++){
    __syncthreads();
    {
      int c = t>>1, kb = (t&1)*16;
      const float* wr = wout + (size_t)c*512 + kt*32 + kb;
      v4f a0 = *(const v4f*)wr, a1 = *(const v4f*)(wr+4);
      v4f a2 = *(const v4f*)(wr+8), a3 = *(const v4f*)(wr+12);
      uint4 u0, u1;
      u0.x = pk2(a0[0], a0[1]); u0.y = pk2(a0[2], a0[3]);
      u0.z = pk2(a1[0], a1[1]); u0.w = pk2(a1[2], a1[3]);
      u1.x = pk2(a2[0], a2[1]); u1.y = pk2(a2[2], a2[3]);
      u1.z = pk2(a3[0], a3[1]); u1.w = pk2(a3[2], a3[3]);
      *(uint4*)&wl[c*40+kb]   = u0;
      *(uint4*)&wl[c*40+kb+8] = u1;
    }
    __syncthreads();
    short8 af[2];
    #pragma unroll
    for (int mt=0;mt<2;mt++){
      union { uint4 u; short8 s; } ua;
      ua.u = *(const uint4*)&wl[(w*32+mt*16+l15)*40 + q*8];
      af[mt] = ua.s;
    }
    int head = kt>>1; int cc0 = (kt&1)*32 + q*8;
    const unsigned short* bp = AOUT + ((size_t)((b*8+head)*S_SP + s0 + l15))*64 + cc0;
    #pragma unroll
    for (int nt=0;nt<4;nt++){
      union { uint4 u; short8 s; } ub;
      ub.u = *(const uint4*)(bp + (size_t)nt*16*64);
      #pragma unroll
      for (int mt=0;mt<2;mt++)
        acc[mt][nt] = __builtin_amdgcn_mfma_f32_16x16x32_bf16(af[mt], ub.s, acc[mt][nt], 0, 0, 0);
    }
  }
  #pragma unroll
  for (int nt=0;nt<4;nt++){
    float p1 = 0.f, p2 = 0.f;
    #pragma unroll
    for (int mt=0;mt<2;mt++)
      #pragma unroll
      for (int r=0;r<4;r++){ float v = acc[mt][nt][r]; p1 += v; p2 += v*v; }
    p1 += __shfl_xor(p1,16,64); p1 += __shfl_xor(p1,32,64);
    p2 += __shfl_xor(p2,16,64); p2 += __shfl_xor(p2,32,64);
    if (q == 0){ lnp[w][0][nt*16+l15] = p1; lnp[w][1][nt*16+l15] = p2; }
  }
  __syncthreads();
  if (t < 64){
    float m = (lnp[0][0][t]+lnp[1][0][t]+lnp[2][0][t]+lnp[3][0][t]) * 0.0078125f;
    float qq = (lnp[0][1][t]+lnp[1][1][t]+lnp[2][1][t]+lnp[3][1][t]) * 0.0078125f;
    float var = fmaxf(qq - m*m, 0.f);
    mbuf[t] = m;
    sbuf[t] = 1.f/(sqrtf(var) + 1e-6f);
  }
  __syncthreads();
  float gs = gamma[0];
  #pragma unroll
  for (int nt=0;nt<4;nt++){
    int sl = nt*16 + l15;
    float mm = mbuf[sl], ssc = sbuf[sl];
    #pragma unroll
    for (int mt=0;mt<2;mt++){
      #pragma unroll
      for (int r=0;r<4;r++){
        int c = w*32 + mt*16 + q*4 + r;
        size_t adr = ((size_t)(b*128+c))*S_SP + s0 + sl;
        float yn = (acc[mt][nt][r]-mm)*ssc;
        OUT[adr] = gs*(ogl[c]*yn + obl[c]) + qsrc[adr];
      }
    }
  }
}

extern "C" void kernel_launch(void* const* d_in, const int* in_sizes, int n_in,
                              void* d_out, int out_size, void* d_ws, size_t ws_size,
                              hipStream_t stream){
  const float* qsrc  = (const float*)d_in[0];
  const float* ctx   = (const float*)d_in[1];
  const float* wq    = (const float*)d_in[2];
  const float* wkv   = (const float*)d_in[3];
  const float* wout  = (const float*)d_in[4];
  const float* ctx_g = (const float*)d_in[5];
  const float* ctx_b = (const float*)d_in[6];
  const float* qs_g  = (const float*)d_in[7];
  const float* qs_b  = (const float*)d_in[8];
  const float* out_g = (const float*)d_in[9];
  const float* out_b = (const float*)d_in[10];
  const float* gamma = (const float*)d_in[11];
  float* OUT = (float*)d_out;
  char* ws = (char*)d_ws;
  float* QP    = (float*)(ws);
  float* SCORE = (float*)(ws + 4096);
  float* MEAN  = (float*)(ws + 16384);
  float* INV   = (float*)(ws + 278528);
  unsigned short* QBF  = (unsigned short*)(ws + 544768);
  unsigned short* KG   = (unsigned short*)(ws + 34099200);
  unsigned short* VGT  = (unsigned short*)(ws + 35147776);
  unsigned short* AOUT = (unsigned short*)(ws + 36196352);
  // W hi/lo alias the KG region (dead until k_gather runs)
  unsigned short* WQh = (unsigned short*)(ws + 34099200);
  unsigned short* WQl = (unsigned short*)(ws + 34230272);
  unsigned short* WKh = (unsigned short*)(ws + 34361344);
  unsigned short* WKl = (unsigned short*)(ws + 34492416);
  // XT hi/lo alias the AOUT region (dead until k_attn runs); ends at 69750784
  unsigned short* XTQh = (unsigned short*)(ws + 36196352);
  unsigned short* XTQl = (unsigned short*)(ws + 44584960);
  unsigned short* XTCh = (unsigned short*)(ws + 52973568);
  unsigned short* XTCl = (unsigned short*)(ws + 61362176);

  hipMemsetAsync(ws, 0, 9216, stream); // QP + SCORE
  k_stats<<<1088, 256, 0, stream>>>(ctx, qsrc, ctx_g, ctx_b, qs_g, qs_b, wq, wkv,
                                    MEAN, INV, XTCh, XTCl, XTQh, XTQl,
                                    WQh, WQl, WKh, WKl);
  k_proj<0><<<512, 256, 0, stream>>>(XTQh, XTQl, WQh, WQl, QBF, QP, SCORE);
  k_proj<1><<<512, 256, 0, stream>>>(XTCh, XTCl, WKh, WKl, QBF, QP, SCORE);
  k_gather<<<512, 256, 0, stream>>>(ctx, wkv, ctx_g, ctx_b, MEAN, INV, SCORE, KG, VGT);
  k_attn<<<1024, 256, 0, stream>>>(QBF, KG, VGT, AOUT);
  k_out<<<512, 256, 0, stream>>>(AOUT, wout, out_g, out_b, gamma, qsrc, OUT);
}

// Round 19
// 297.391 us; speedup vs baseline: 1.2154x; 1.0051x over previous
//
#include <hip/hip_runtime.h>
#include <hip/hip_bf16.h>

#define S_SP 16384
#define NKV 512

typedef short short8 __attribute__((ext_vector_type(8)));
typedef float v4f   __attribute__((ext_vector_type(4)));

__device__ __forceinline__ unsigned short f2bf(float x){
  union { float f; unsigned u; } v; v.f = x;
  unsigned r = v.u + 0x7FFFu + ((v.u >> 16) & 1u);
  return (unsigned short)(r >> 16);
}
__device__ __forceinline__ float bf2f(unsigned short h){
  union { unsigned u; float f; } v; v.u = ((unsigned)h) << 16; return v.f;
}

#if defined(__has_builtin)
#if __has_builtin(__builtin_amdgcn_cvt_pk_bf16_f32)
#define HAVE_PKBF 1
#endif
#endif

__device__ __forceinline__ unsigned pk2(float a, float b){
#ifdef HAVE_PKBF
  typedef __bf16 bf16x2 __attribute__((ext_vector_type(2)));
  union { bf16x2 v; unsigned u; } r;
  r.v = __builtin_amdgcn_cvt_pk_bf16_f32(a, b);
  return r.u;
#else
  return (unsigned)f2bf(a) | ((unsigned)f2bf(b) << 16);
#endif
}

__device__ __forceinline__ short8 u2s8(uint4 u){
  union { uint4 u; short8 s; } x; x.u = u; return x.s;
}

// ---------------- K1: channel-LN stats + pre-LN'd transposed bf16 hi/lo copy
// Blocks [0,1024): stats + XT emit. Blocks [1024,1088): W hi/lo split.
__global__ __launch_bounds__(256) void k_stats(const float* __restrict__ ctx,
                                               const float* __restrict__ qs,
                                               const float* __restrict__ ctx_g,
                                               const float* __restrict__ ctx_b,
                                               const float* __restrict__ qs_g,
                                               const float* __restrict__ qs_b,
                                               const float* __restrict__ wq,
                                               const float* __restrict__ wkv,
                                               float* __restrict__ MEAN,
                                               float* __restrict__ INV,
                                               unsigned short* __restrict__ XTC_hi,
                                               unsigned short* __restrict__ XTC_lo,
                                               unsigned short* __restrict__ XTQ_hi,
                                               unsigned short* __restrict__ XTQ_lo,
                                               unsigned short* __restrict__ WQh,
                                               unsigned short* __restrict__ WQl,
                                               unsigned short* __restrict__ WKh,
                                               unsigned short* __restrict__ WKl){
  __shared__ float r1[4][64];
  __shared__ float r2[4][64];
  __shared__ float mb[64], ib[64];
  __shared__ __align__(16) unsigned short TH[64*136];
  __shared__ __align__(16) unsigned short TL[64*136];
  int bx = blockIdx.x;
  int t = threadIdx.x;
  if (bx >= 1024){ // W hi/lo split: wq (512x128) then wkv K-half (512x128)
    int wb = bx - 1024;
    int isK = wb >> 5;
    size_t i8 = ((size_t)(wb & 31)*256 + t)*8;
    const float* srcw = isK ? wkv : wq;
    unsigned short* dh = isK ? WKh : WQh;
    unsigned short* dl = isK ? WKl : WQl;
    v4f a  = *(const v4f*)(srcw + i8);
    v4f b2 = *(const v4f*)(srcw + i8 + 4);
    unsigned short h[8], l[8];
    #pragma unroll
    for (int i=0;i<4;i++){
      h[i]   = f2bf(a[i]);  l[i]   = f2bf(a[i]  - bf2f(h[i]));
      h[i+4] = f2bf(b2[i]); l[i+4] = f2bf(b2[i] - bf2f(h[i+4]));
    }
    uint4 uh, ul;
    uh.x = (unsigned)h[0] | ((unsigned)h[1]<<16);
    uh.y = (unsigned)h[2] | ((unsigned)h[3]<<16);
    uh.z = (unsigned)h[4] | ((unsigned)h[5]<<16);
    uh.w = (unsigned)h[6] | ((unsigned)h[7]<<16);
    ul.x = (unsigned)l[0] | ((unsigned)l[1]<<16);
    ul.y = (unsigned)l[2] | ((unsigned)l[3]<<16);
    ul.z = (unsigned)l[4] | ((unsigned)l[5]<<16);
    ul.w = (unsigned)l[6] | ((unsigned)l[7]<<16);
    *(uint4*)(dh + i8) = uh;
    *(uint4*)(dl + i8) = ul;
    return;
  }
  int tt = bx >> 9; int b = (bx >> 8) & 1; int sc = bx & 255;
  int sv = t & 63, cg = t >> 6;
  int s = sc*64 + sv;
  const float* src = (tt ? qs : ctx) + ((size_t)b*128 + cg*32)*S_SP + s;
  const float* G  = tt ? qs_g : ctx_g;
  const float* Bv = tt ? qs_b : ctx_b;
  float xv[32];
  float sum = 0.f, ss = 0.f;
  #pragma unroll
  for (int c = 0; c < 32; c++){
    float v = src[(size_t)c*S_SP];
    xv[c] = v;
    sum += v; ss += v*v;
  }
  r1[cg][sv] = sum; r2[cg][sv] = ss;
  __syncthreads();
  if (t < 64){
    float sm = r1[0][t]+r1[1][t]+r1[2][t]+r1[3][t];
    float sq = r2[0][t]+r2[1][t]+r2[2][t]+r2[3][t];
    float mean = sm * 0.0078125f;
    float var  = fmaxf(sq * 0.0078125f - mean*mean, 0.f);
    float inv  = 1.f/(sqrtf(var) + 1e-6f);
    int o = tt*2*S_SP + b*S_SP + sc*64 + t;
    MEAN[o] = mean; INV[o] = inv;
    mb[t] = mean; ib[t] = inv;
  }
  __syncthreads();
  float m = mb[sv], iv = ib[sv];
  #pragma unroll
  for (int i = 0; i < 32; i += 2){
    int c = cg*32 + i;
    float y0 = G[c]  *(xv[i]  -m)*iv + Bv[c];
    float y1 = G[c+1]*(xv[i+1]-m)*iv + Bv[c+1];
    unsigned short h0 = f2bf(y0), h1 = f2bf(y1);
    unsigned short l0 = f2bf(y0 - bf2f(h0)), l1 = f2bf(y1 - bf2f(h1));
    *(unsigned*)&TH[sv*136 + c] = (unsigned)h0 | ((unsigned)h1 << 16);
    *(unsigned*)&TL[sv*136 + c] = (unsigned)l0 | ((unsigned)l1 << 16);
  }
  __syncthreads();
  int row = t >> 2, seg = (t & 3) * 32;
  unsigned short* XH = tt ? XTQ_hi : XTC_hi;
  unsigned short* XL = tt ? XTQ_lo : XTC_lo;
  size_t go = ((size_t)b*S_SP + sc*64 + row)*128 + seg;
  #pragma unroll
  for (int k2 = 0; k2 < 4; k2++){
    *(uint4*)(XH + go + k2*8) = *(const uint4*)&TH[row*136 + seg + k2*8];
    *(uint4*)(XL + go + k2*8) = *(const uint4*)&TL[row*136 + seg + k2*8];
  }
}

// ---------------- K2: projection as split-bf16 3-pass MFMA ------------------
// D = Ah*Bh + Ah*Bl + Al*Bh  ~  fp32-accurate (missing Al*Bl ~2^-18).
template<int ISK>
__global__ __launch_bounds__(256, 2) void k_proj(
    const unsigned short* __restrict__ XH, const unsigned short* __restrict__ XL,
    const unsigned short* __restrict__ WH, const unsigned short* __restrict__ WL,
    unsigned short* __restrict__ QBF, float* __restrict__ QP,
    float* __restrict__ SCORE){
  __shared__ float qpl[128];
  __shared__ float qacc[128];  // !ISK: block-reduced q_probe
  __shared__ float wacc[64];   // ISK: block-reduced w-axis scores [head*32+w]
  int bx = blockIdx.x;
  int og = bx >> 7, b = (bx >> 6) & 1, stile = bx & 63;
  int t = threadIdx.x, wvi = t >> 6, lane = t & 63;
  int quad = lane >> 4, l15 = lane & 15;
  int sw0 = stile*256 + wvi*64;
  int bh0 = b*8 + og*2;
  if (ISK){
    if (t < 128) qpl[t] = QP[bh0*64 + t];
    if (t < 64) wacc[t] = 0.f;
    __syncthreads();
  } else {
    if (t < 128) qacc[t] = 0.f;  // ordered by the epilogue barrier
  }
  v4f acc[8][4];
  #pragma unroll
  for (int i=0;i<8;i++)
    #pragma unroll
    for (int j=0;j<4;j++) acc[i][j] = (v4f){0.f,0.f,0.f,0.f};
  size_t wrow = ((size_t)(og*128 + l15))*128 + quad*8;
  size_t xrow = ((size_t)b*S_SP + sw0 + l15)*128 + quad*8;
  #pragma unroll 1
  for (int ks=0; ks<4; ks++){
    int ko = ks*32;
    uint4 bhv[4], blv[4], av[8];
    #pragma unroll
    for (int nt=0;nt<4;nt++){
      bhv[nt] = *(const uint4*)(XH + xrow + nt*2048 + ko);
      blv[nt] = *(const uint4*)(XL + xrow + nt*2048 + ko);
    }
    #pragma unroll
    for (int mt=0;mt<8;mt++) av[mt] = *(const uint4*)(WH + wrow + mt*2048 + ko);
    #pragma unroll
    for (int mt=0;mt<8;mt++){
      short8 am = u2s8(av[mt]);
      #pragma unroll
      for (int nt=0;nt<4;nt++)
        acc[mt][nt] = __builtin_amdgcn_mfma_f32_16x16x32_bf16(am, u2s8(bhv[nt]), acc[mt][nt], 0, 0, 0);
      #pragma unroll
      for (int nt=0;nt<4;nt++)
        acc[mt][nt] = __builtin_amdgcn_mfma_f32_16x16x32_bf16(am, u2s8(blv[nt]), acc[mt][nt], 0, 0, 0);
    }
    #pragma unroll
    for (int mt=0;mt<8;mt++){
      short8 am = u2s8(*(const uint4*)(WL + wrow + mt*2048 + ko));
      #pragma unroll
      for (int nt=0;nt<4;nt++)
        acc[mt][nt] = __builtin_amdgcn_mfma_f32_16x16x32_bf16(am, u2s8(bhv[nt]), acc[mt][nt], 0, 0, 0);
    }
  }
  // per-head l2norm inverses (per spatial col): in-lane + quad shfl reduce
  float inv0[4], inv1[4];
  #pragma unroll
  for (int nt=0;nt<4;nt++){
    float p0 = 0.f, p1 = 0.f;
    #pragma unroll
    for (int mt=0;mt<4;mt++)
      #pragma unroll
      for (int r=0;r<4;r++){
        p0 += acc[mt][nt][r]*acc[mt][nt][r];
        p1 += acc[mt+4][nt][r]*acc[mt+4][nt][r];
      }
    p0 += __shfl_xor(p0,16,64); p0 += __shfl_xor(p0,32,64);
    p1 += __shfl_xor(p1,16,64); p1 += __shfl_xor(p1,32,64);
    inv0[nt] = 1.f/fmaxf(sqrtf(p0),1e-12f);
    inv1[nt] = 1.f/fmaxf(sqrtf(p1),1e-12f);
  }
  if (!ISK){
    #pragma unroll
    for (int mt=0;mt<8;mt++)
      #pragma unroll
      for (int nt=0;nt<4;nt++){
        float iv = (mt<4) ? inv0[nt] : inv1[nt];
        #pragma unroll
        for (int r=0;r<4;r++) acc[mt][nt][r] *= iv;
      }
    // QBF: [bh][s][64c] bf16 (layout k_attn expects)
    #pragma unroll
    for (int mt=0;mt<8;mt++){
      int bh = bh0 + (mt>>2);
      #pragma unroll
      for (int nt=0;nt<4;nt++){
        int s = sw0 + nt*16 + l15;
        uint2 wv;
        wv.x = pk2(acc[mt][nt][0], acc[mt][nt][1]);
        wv.y = pk2(acc[mt][nt][2], acc[mt][nt][3]);
        *(uint2*)(QBF + ((size_t)bh*S_SP + s)*64 + (mt&3)*16 + quad*4) = wv;
      }
    }
    __syncthreads();  // orders qacc zeroing before LDS atomics
    #pragma unroll
    for (int mt=0;mt<8;mt++){
      #pragma unroll
      for (int r=0;r<4;r++){
        float v = acc[mt][0][r]+acc[mt][1][r]+acc[mt][2][r]+acc[mt][3][r];
        v += __shfl_xor(v,1,64); v += __shfl_xor(v,2,64);
        v += __shfl_xor(v,4,64); v += __shfl_xor(v,8,64);
        if (l15 == 0)
          atomicAdd(&qacc[(mt>>2)*64 + (mt&3)*16 + quad*4 + r], v);
      }
    }
    __syncthreads();
    if (t < 128) atomicAdd(QP + bh0*64 + t, qacc[t]);
  } else {
    float v0[4] = {0,0,0,0}, v1[4] = {0,0,0,0};
    #pragma unroll
    for (int mt=0;mt<8;mt++){
      #pragma unroll
      for (int r=0;r<4;r++){
        float w = qpl[mt*16 + quad*4 + r];
        #pragma unroll
        for (int nt=0;nt<4;nt++){
          float av = fabsf(acc[mt][nt][r]) * w;
          if (mt < 4) v0[nt] += av; else v1[nt] += av;
        }
      }
    }
    #pragma unroll
    for (int nt=0;nt<4;nt++){
      v0[nt] += __shfl_xor(v0[nt],16,64); v0[nt] += __shfl_xor(v0[nt],32,64);
      v1[nt] += __shfl_xor(v1[nt],16,64); v1[nt] += __shfl_xor(v1[nt],32,64);
      v0[nt] *= inv0[nt]; v1[nt] *= inv1[nt];
    }
    // s = stile*256 + wvi*64 + nt*16 + l15:
    //   w = (nt&1)*16 + l15 ; h = (stile&3)*8 + wvi*2 + (nt>>1) ; d = stile>>2
    float w00 = v0[0]+v0[2], w10 = v0[1]+v0[3];
    float w01 = v1[0]+v1[2], w11 = v1[1]+v1[3];
    float h00 = v0[0]+v0[1], h01 = v0[2]+v0[3];
    float h10 = v1[0]+v1[1], h11 = v1[2]+v1[3];
    #pragma unroll
    for (int mm=1; mm<16; mm<<=1){
      h00 += __shfl_xor(h00,mm,64); h01 += __shfl_xor(h01,mm,64);
      h10 += __shfl_xor(h10,mm,64); h11 += __shfl_xor(h11,mm,64);
    }
    if (lane < 16){
      atomicAdd(&wacc[l15],      w00);
      atomicAdd(&wacc[16+l15],   w10);
      atomicAdd(&wacc[32+l15],   w01);
      atomicAdd(&wacc[48+l15],   w11);
    }
    if (lane == 0){
      int hb = 16 + (stile&3)*8 + wvi*2;
      atomicAdd(SCORE + bh0*80 + hb,     h00);
      atomicAdd(SCORE + bh0*80 + hb + 1, h01);
      atomicAdd(SCORE + (bh0+1)*80 + hb,     h10);
      atomicAdd(SCORE + (bh0+1)*80 + hb + 1, h11);
      atomicAdd(SCORE + bh0*80 + (stile>>2), h00+h01);
      atomicAdd(SCORE + (bh0+1)*80 + (stile>>2), h10+h11);
    }
    __syncthreads();
    if (t < 64) atomicAdd(SCORE + (bh0 + (t>>5))*80 + 48 + (t&31), wacc[t]);
  }
}

// ---------------- K4: topk (inlined, wave 0) + gather-recompute ------------
// xln sourced from XTC hi/lo (s-major, LN already applied): 2x256B contiguous
// reads per site vs 128 scattered stride-16384 lines (est. ~128MB -> ~2MB).
__global__ __launch_bounds__(256) void k_gather(
    const unsigned short* __restrict__ XH, const unsigned short* __restrict__ XL,
    const float* __restrict__ wkv, const float* __restrict__ SCORE,
    unsigned short* __restrict__ KG, unsigned short* __restrict__ VGT){
  __shared__ float wlds[64*129];
  __shared__ float xln[32*128];
  __shared__ float scb[80];
  __shared__ int sidx[24];
  int bx = blockIdx.x;
  int bh = bx >> 5, jc = (bx >> 1) & 15, type = bx & 1;
  int head = bh & 7, b = bh >> 3;
  int t = threadIdx.x;
  if (t < 80) scb[t] = SCORE[bh*80 + t];
  {
    int oc = t>>2, ks = (t&3)*32;
    const float* wr = wkv + ((size_t)(type*512 + head*64 + oc))*128 + ks;
    #pragma unroll 8
    for (int i=0;i<32;i++) wlds[oc*129 + ks + i] = wr[i];
  }
  __syncthreads();
  if (t < 64){ // wave 0: butterfly top-8 per axis (ties -> lowest idx)
    #pragma unroll 1
    for (int a=0;a<3;a++){
      int n = a ? 32 : 16;
      int off = (a==0) ? 0 : (a==1 ? 16 : 48);
      float v = (t < n) ? scb[off+t] : -3.4e38f;
      #pragma unroll 1
      for (int it=0; it<8; it++){
        float bv = v; int bi = t;
        #pragma unroll
        for (int mm=1; mm<32; mm<<=1){
          float ov = __shfl_xor(bv, mm, 64);
          int oi = __shfl_xor(bi, mm, 64);
          if (ov > bv || (ov == bv && oi < bi)){ bv = ov; bi = oi; }
        }
        if (t == bi) v = -3.4e38f;
        if (t == 0) sidx[a*8+it] = bi;
      }
    }
  }
  __syncthreads();
  {
    int jl = t>>3, seg = (t&7)*16;
    int jj = jc*32 + jl;
    int dsel = sidx[jj>>6], hsel = sidx[8 + ((jj>>3)&7)], wsel = sidx[16 + (jj&7)];
    int sj = dsel*1024 + hsel*32 + wsel;
    size_t xo = ((size_t)b*S_SP + sj)*128 + seg;
    union { uint4 u; unsigned short s[8]; } h0, h1, l0, l1;
    h0.u = *(const uint4*)(XH + xo);
    h1.u = *(const uint4*)(XH + xo + 8);
    l0.u = *(const uint4*)(XL + xo);
    l1.u = *(const uint4*)(XL + xo + 8);
    #pragma unroll
    for (int i=0;i<8;i++){
      xln[jl*128 + seg + i]     = bf2f(h0.s[i]) + bf2f(l0.s[i]);
      xln[jl*128 + seg + 8 + i] = bf2f(h1.s[i]) + bf2f(l1.s[i]);
    }
  }
  __syncthreads();
  int c = t & 63, jg = t >> 6;
  float accv[8] = {};
  #pragma unroll 4
  for (int k=0;k<128;k++){
    float wv = wlds[c*129 + k];
    #pragma unroll
    for (int m=0;m<8;m++) accv[m] += wv * xln[(jg + 4*m)*128 + k];
  }
  #pragma unroll
  for (int m=0;m<8;m++){
    int jj = jc*32 + jg + 4*m;
    float a = accv[m];
    if (type == 0){
      float sq = a*a;
      #pragma unroll
      for (int mm=32; mm; mm>>=1) sq += __shfl_xor(sq, mm, 64);
      float rn = 1.f/fmaxf(sqrtf(sq), 1e-12f);
      KG[((size_t)bh*NKV + jj)*64 + c] = f2bf(a*rn);
    } else {
      VGT[((size_t)bh*64 + c)*NKV + jj] = f2bf(a);
    }
  }
}

// ---------------- K5: attention, S^T=K.Q^T / O^T=V^T.P^T, fixed-max softmax -
// LDS: XOR-swizzled 16B blocks (blk ^= row&7 / row&3) on kst/vst; per-wave
// pst. 48 KiB total -> 3 blocks/CU. |sim|<=1 => softmax == exp(s-1)/sum.
__global__ __launch_bounds__(256) void k_attn(const unsigned short* __restrict__ QBF,
    const unsigned short* __restrict__ KG, const unsigned short* __restrict__ VGT,
    unsigned short* __restrict__ AOUT){
  __shared__ __align__(16) unsigned short kst[128*64];   // K chunk [j][c], swz
  __shared__ __align__(16) unsigned short vst[64*128];   // V chunk [c][j], swz
  __shared__ __align__(16) unsigned short pst[4][64*32]; // per-wave P [q][j], swz
  int bx = blockIdx.x;
  int bh = bx >> 6, qb = bx & 63;
  int t = threadIdx.x;
  int wvi = t >> 6, lane = t & 63;
  int quad = lane >> 4, l15 = lane & 15;
  int q0 = qb*256 + wvi*64;
  const unsigned short* kgb = KG + (size_t)bh*NKV*64;
  const unsigned short* vgb = VGT + (size_t)bh*64*NKV;
  short8 bq[4][2];
  #pragma unroll
  for (int qt=0; qt<4; qt++){
    const unsigned short* qp_ = QBF + ((size_t)bh*S_SP + q0 + qt*16 + l15)*64 + quad*8;
    union { uint4 u; short8 s; } u0, u1;
    u0.u = *(const uint4*)(qp_);
    u1.u = *(const uint4*)(qp_ + 32);
    bq[qt][0] = u0.s; bq[qt][1] = u1.s;
  }
  v4f oacc[4][4]; // [ct][qt]: O^T tile: col=q=l15, row=c=ct*16+quad*4+r
  #pragma unroll
  for (int i=0;i<4;i++)
    #pragma unroll
    for (int j=0;j<4;j++) oacc[i][j] = (v4f){0.f,0.f,0.f,0.f};
  float lsum[4] = {0.f,0.f,0.f,0.f};
  unsigned short* pw = pst[wvi];
  for (int ch=0; ch<4; ch++){
    __syncthreads();
    { // stage K chunk [128 j][64 c]; block swz: blk' = blk ^ (j&7)
      int jl = t>>1, bb = (t&1)*4;
      const unsigned short* sp = kgb + (size_t)(ch*128 + jl)*64 + (t&1)*32;
      unsigned short* dp = kst + jl*64;
      int sw = jl & 7;
      #pragma unroll
      for (int i=0;i<4;i++) *(uint4*)(dp + (((bb+i)^sw)*8)) = *(const uint4*)(sp + i*8);
    }
    { // stage V chunk [64 c][128 j]; block swz: blk' = blk ^ (c&7)
      int cc = t>>2, bb = (t&3)*4;
      const unsigned short* sp = vgb + (size_t)cc*NKV + ch*128 + (t&3)*32;
      unsigned short* dp = vst + cc*128;
      int sw = cc & 7;
      #pragma unroll
      for (int i=0;i<4;i++) *(uint4*)(dp + (((bb+i)^sw)*8)) = *(const uint4*)(sp + i*8);
    }
    __syncthreads();
    #pragma unroll
    for (int sub=0; sub<4; sub++){ // 32 j per sub
      v4f s[2][4];
      #pragma unroll
      for (int j2=0; j2<2; j2++){
        int jr = (sub*2 + j2)*16 + l15;
        const unsigned short* kr = kst + jr*64;
        int sk = jr & 7;
        union { uint4 u; short8 s; } a0, a1;
        a0.u = *(const uint4*)(kr + ((quad^sk)*8));
        a1.u = *(const uint4*)(kr + (((quad+4)^sk)*8));
        __builtin_amdgcn_s_setprio(1);
        #pragma unroll
        for (int qt=0; qt<4; qt++){
          v4f z = {0.f,0.f,0.f,0.f};
          z = __builtin_amdgcn_mfma_f32_16x16x32_bf16(a0.s, bq[qt][0], z, 0, 0, 0);
          z = __builtin_amdgcn_mfma_f32_16x16x32_bf16(a1.s, bq[qt][1], z, 0, 0, 0);
          s[j2][qt] = z;
        }
        __builtin_amdgcn_s_setprio(0);
      }
      #pragma unroll
      for (int j2=0; j2<2; j2++){
        #pragma unroll
        for (int qt=0; qt<4; qt++){
          v4f p;
          #pragma unroll
          for (int r=0;r<4;r++) p[r] = __expf(s[j2][qt][r] - 1.0f);
          lsum[qt] += p[0]+p[1]+p[2]+p[3];
          uint2 wv;
          wv.x = pk2(p[0], p[1]);
          wv.y = pk2(p[2], p[3]);
          int qr = qt*16 + l15;
          *(uint2*)&pw[qr*32 + (((j2*2+(quad>>1))^(qr&3))*8) + (quad&1)*4] = wv;
        }
      }
      short8 bp[4];
      #pragma unroll
      for (int qt=0; qt<4; qt++){
        int qr = qt*16 + l15;
        union { uint4 u; short8 s; } ub;
        ub.u = *(const uint4*)&pw[qr*32 + ((quad^(qr&3))*8)];
        bp[qt] = ub.s;
      }
      #pragma unroll
      for (int ct=0; ct<4; ct++){
        int cr = ct*16 + l15;
        union { uint4 u; short8 s; } av;
        av.u = *(const uint4*)&vst[cr*128 + (((sub*4+quad)^(cr&7))*8)];
        __builtin_amdgcn_s_setprio(1);
        #pragma unroll
        for (int qt=0; qt<4; qt++)
          oacc[ct][qt] = __builtin_amdgcn_mfma_f32_16x16x32_bf16(av.s, bp[qt], oacc[ct][qt], 0, 0, 0);
        __builtin_amdgcn_s_setprio(0);
      }
    }
  }
  float rl[4];
  #pragma unroll
  for (int qt=0; qt<4; qt++){
    float l = lsum[qt];
    l += __shfl_xor(l, 16, 64);
    l += __shfl_xor(l, 32, 64);
    rl[qt] = 1.f/l;
  }
  #pragma unroll
  for (int qt=0; qt<4; qt++){
    #pragma unroll
    for (int ct=0; ct<4; ct++){
      v4f o = oacc[ct][qt];
      uint2 wv;
      wv.x = pk2(o[0]*rl[qt], o[1]*rl[qt]);
      wv.y = pk2(o[2]*rl[qt], o[3]*rl[qt]);
      *(uint2*)(AOUT + ((size_t)bh*S_SP + q0 + qt*16 + l15)*64 + ct*16 + quad*4) = wv;
    }
  }
}

// ---------------- K6: out-projection via MFMA bf16 + LN + residual ---------
__global__ __launch_bounds__(256) void k_out(const unsigned short* __restrict__ AOUT,
    const float* __restrict__ wout, const float* __restrict__ out_g,
    const float* __restrict__ out_b, const float* __restrict__ gamma,
    const float* __restrict__ qsrc, float* __restrict__ OUT){
  __shared__ __align__(16) unsigned short wl[128*40];
  __shared__ float lnp[4][2][64];
  __shared__ float mbuf[64], sbuf[64], ogl[128], obl[128];
  int bx = blockIdx.x; int b = bx>>8; int stile = bx&255; int s0 = stile*64;
  int t = threadIdx.x; int w = t>>6; int lane = t&63;
  int q = lane>>4; int l15 = lane&15;
  if (t < 128){ ogl[t] = out_g[t]; obl[t] = out_b[t]; }
  v4f acc[2][4];
  #pragma unroll
  for (int i=0;i<2;i++)
    #pragma unroll
    for (int j=0;j<4;j++) acc[i][j] = (v4f){0.f,0.f,0.f,0.f};
  for (int kt=0; kt<16; kt++){
    __syncthreads();
    {
      int c = t>>1, kb = (t&1)*16;
      const float* wr = wout + (size_t)c*512 + kt*32 + kb;
      v4f a0 = *(const v4f*)wr, a1 = *(const v4f*)(wr+4);
      v4f a2 = *(const v4f*)(wr+8), a3 = *(const v4f*)(wr+12);
      uint4 u0, u1;
      u0.x = pk2(a0[0], a0[1]); u0.y = pk2(a0[2], a0[3]);
      u0.z = pk2(a1[0], a1[1]); u0.w = pk2(a1[2], a1[3]);
      u1.x = pk2(a2[0], a2[1]); u1.y = pk2(a2[2], a2[3]);
      u1.z = pk2(a3[0], a3[1]); u1.w = pk2(a3[2], a3[3]);
      *(uint4*)&wl[c*40+kb]   = u0;
      *(uint4*)&wl[c*40+kb+8] = u1;
    }
    __syncthreads();
    short8 af[2];
    #pragma unroll
    for (int mt=0;mt<2;mt++){
      union { uint4 u; short8 s; } ua;
      ua.u = *(const uint4*)&wl[(w*32+mt*16+l15)*40 + q*8];
      af[mt] = ua.s;
    }
    int head = kt>>1; int cc0 = (kt&1)*32 + q*8;
    const unsigned short* bp = AOUT + ((size_t)((b*8+head)*S_SP + s0 + l15))*64 + cc0;
    #pragma unroll
    for (int nt=0;nt<4;nt++){
      union { uint4 u; short8 s; } ub;
      ub.u = *(const uint4*)(bp + (size_t)nt*16*64);
      #pragma unroll
      for (int mt=0;mt<2;mt++)
        acc[mt][nt] = __builtin_amdgcn_mfma_f32_16x16x32_bf16(af[mt], ub.s, acc[mt][nt], 0, 0, 0);
    }
  }
  #pragma unroll
  for (int nt=0;nt<4;nt++){
    float p1 = 0.f, p2 = 0.f;
    #pragma unroll
    for (int mt=0;mt<2;mt++)
      #pragma unroll
      for (int r=0;r<4;r++){ float v = acc[mt][nt][r]; p1 += v; p2 += v*v; }
    p1 += __shfl_xor(p1,16,64); p1 += __shfl_xor(p1,32,64);
    p2 += __shfl_xor(p2,16,64); p2 += __shfl_xor(p2,32,64);
    if (q == 0){ lnp[w][0][nt*16+l15] = p1; lnp[w][1][nt*16+l15] = p2; }
  }
  __syncthreads();
  if (t < 64){
    float m = (lnp[0][0][t]+lnp[1][0][t]+lnp[2][0][t]+lnp[3][0][t]) * 0.0078125f;
    float qq = (lnp[0][1][t]+lnp[1][1][t]+lnp[2][1][t]+lnp[3][1][t]) * 0.0078125f;
    float var = fmaxf(qq - m*m, 0.f);
    mbuf[t] = m;
    sbuf[t] = 1.f/(sqrtf(var) + 1e-6f);
  }
  __syncthreads();
  float gs = gamma[0];
  #pragma unroll
  for (int nt=0;nt<4;nt++){
    int sl = nt*16 + l15;
    float mm = mbuf[sl], ssc = sbuf[sl];
    #pragma unroll
    for (int mt=0;mt<2;mt++){
      #pragma unroll
      for (int r=0;r<4;r++){
        int c = w*32 + mt*16 + q*4 + r;
        size_t adr = ((size_t)(b*128+c))*S_SP + s0 + sl;
        float yn = (acc[mt][nt][r]-mm)*ssc;
        OUT[adr] = gs*(ogl[c]*yn + obl[c]) + qsrc[adr];
      }
    }
  }
}

extern "C" void kernel_launch(void* const* d_in, const int* in_sizes, int n_in,
                              void* d_out, int out_size, void* d_ws, size_t ws_size,
                              hipStream_t stream){
  const float* qsrc  = (const float*)d_in[0];
  const float* ctx   = (const float*)d_in[1];
  const float* wq    = (const float*)d_in[2];
  const float* wkv   = (const float*)d_in[3];
  const float* wout  = (const float*)d_in[4];
  const float* ctx_g = (const float*)d_in[5];
  const float* ctx_b = (const float*)d_in[6];
  const float* qs_g  = (const float*)d_in[7];
  const float* qs_b  = (const float*)d_in[8];
  const float* out_g = (const float*)d_in[9];
  const float* out_b = (const float*)d_in[10];
  const float* gamma = (const float*)d_in[11];
  float* OUT = (float*)d_out;
  char* ws = (char*)d_ws;
  float* QP    = (float*)(ws);
  float* SCORE = (float*)(ws + 4096);
  float* MEAN  = (float*)(ws + 16384);
  float* INV   = (float*)(ws + 278528);
  unsigned short* QBF  = (unsigned short*)(ws + 544768);
  unsigned short* KG   = (unsigned short*)(ws + 34099200);
  unsigned short* VGT  = (unsigned short*)(ws + 35147776);
  unsigned short* AOUT = (unsigned short*)(ws + 36196352);
  // W hi/lo alias the KG region (dead until k_gather runs)
  unsigned short* WQh = (unsigned short*)(ws + 34099200);
  unsigned short* WQl = (unsigned short*)(ws + 34230272);
  unsigned short* WKh = (unsigned short*)(ws + 34361344);
  unsigned short* WKl = (unsigned short*)(ws + 34492416);
  // XT hi/lo alias the AOUT region (dead until k_attn runs); ends at 69750784
  unsigned short* XTQh = (unsigned short*)(ws + 36196352);
  unsigned short* XTQl = (unsigned short*)(ws + 44584960);
  unsigned short* XTCh = (unsigned short*)(ws + 52973568);
  unsigned short* XTCl = (unsigned short*)(ws + 61362176);

  hipMemsetAsync(ws, 0, 9216, stream); // QP + SCORE
  k_stats<<<1088, 256, 0, stream>>>(ctx, qsrc, ctx_g, ctx_b, qs_g, qs_b, wq, wkv,
                                    MEAN, INV, XTCh, XTCl, XTQh, XTQl,
                                    WQh, WQl, WKh, WKl);
  k_proj<0><<<512, 256, 0, stream>>>(XTQh, XTQl, WQh, WQl, QBF, QP, SCORE);
  k_proj<1><<<512, 256, 0, stream>>>(XTCh, XTCl, WKh, WKl, QBF, QP, SCORE);
  k_gather<<<512, 256, 0, stream>>>(XTCh, XTCl, wkv, SCORE, KG, VGT);
  k_attn<<<1024, 256, 0, stream>>>(QBF, KG, VGT, AOUT);
  k_out<<<512, 256, 0, stream>>>(AOUT, wout, out_g, out_b, gamma, qsrc, OUT);
}